// Round 1
// baseline (26295.667 us; speedup 1.0000x reference)
//
#include <hip/hip_runtime.h>
#include <math.h>

#define BB  32
#define SQl 200
#define SKV 200
#define DD  1024
#define NH  16
#define HDm 64
#define NL  6
#define FFD 2048

// ---------------- embedding + sinusoidal positional encoding ----------------
__global__ __launch_bounds__(256) void embed_pe_kernel(const int* __restrict__ qids,
                                                       const float* __restrict__ emb,
                                                       float* __restrict__ x) {
  int idx = blockIdx.x * 256 + threadIdx.x;   // over BB*SQl*DD = 6,553,600
  int d   = idx & (DD - 1);
  int row = idx >> 10;                        // DD = 1024
  int s   = row % SQl;
  int tok = qids[row];
  float expo = (float)(d & ~1) * (1.0f / (float)DD);
  float dv   = powf(10000.0f, expo);
  float ang  = (float)s / dv;
  float pe   = (d & 1) ? cosf(ang) : sinf(ang);
  x[idx] = emb[(size_t)tok * DD + d] + pe;
}

// ---------------- LayerNorm: one block (256 threads) per row of 1024 ----------------
__global__ __launch_bounds__(256) void ln_kernel(const float* __restrict__ in,
                                                 const float* __restrict__ gam,
                                                 const float* __restrict__ bet,
                                                 float* __restrict__ out) {
  const int row = blockIdx.x;
  const int tid = threadIdx.x;
  const float4 xv = *(const float4*)&in[(size_t)row * DD + tid * 4];
  float s  = xv.x + xv.y + xv.z + xv.w;
  float sq = xv.x * xv.x + xv.y * xv.y + xv.z * xv.z + xv.w * xv.w;

  __shared__ float rs[256];
  __shared__ float rq[256];
  rs[tid] = s; rq[tid] = sq;
  __syncthreads();
  for (int st = 128; st > 0; st >>= 1) {
    if (tid < st) { rs[tid] += rs[tid + st]; rq[tid] += rq[tid + st]; }
    __syncthreads();
  }
  const float m   = rs[0] * (1.0f / (float)DD);
  const float var = rq[0] * (1.0f / (float)DD) - m * m;
  const float inv = rsqrtf(var + 1e-9f);

  float4 ov;
  const int c = tid * 4;
  ov.x = (xv.x - m) * inv * gam[c + 0] + bet[c + 0];
  ov.y = (xv.y - m) * inv * gam[c + 1] + bet[c + 1];
  ov.z = (xv.z - m) * inv * gam[c + 2] + bet[c + 2];
  ov.w = (xv.w - m) * inv * gam[c + 3] + bet[c + 3];
  *(float4*)&out[(size_t)row * DD + c] = ov;
}

// ---------------- f32 tiled GEMM: C[M,N] (+)= A[M,K] @ W[K,N] + bias ----------------
// 128x128 tile, BK=8, 256 threads, 8x8 micro-tile per thread.
template <int RELU, int ACC>
__global__ __launch_bounds__(256) void gemm_f32(const float* __restrict__ A,
                                                const float* __restrict__ W,
                                                const float* __restrict__ bias,
                                                float* __restrict__ C,
                                                int M, int N, int K) {
  __shared__ float As[8][128];   // [k][m]
  __shared__ float Ws[8][128];   // [k][n]
  const int tid = threadIdx.x;
  const int bn  = blockIdx.x * 128;
  const int bm  = blockIdx.y * 128;
  const int tx  = tid & 15;
  const int ty  = tid >> 4;
  const int ar  = tid >> 1;            // 0..127 (A tile row)
  const int ac  = (tid & 1) * 4;       // 0 or 4 (A tile k-offset)
  const int wr  = tid >> 5;            // 0..7  (W tile k-row)
  const int wc  = (tid & 31) * 4;      // 0..124 (W tile col)

  float acc[8][8] = {};

  const float* Aptr = A + (size_t)(bm + ar) * K + ac;
  const float* Wptr = W + (size_t)wr * N + bn + wc;

  for (int k0 = 0; k0 < K; k0 += 8) {
    const float4 av = *(const float4*)(Aptr + k0);
    const float4 wv = *(const float4*)(Wptr + (size_t)k0 * N);
    __syncthreads();   // previous iteration's LDS reads done
    As[ac + 0][ar] = av.x;
    As[ac + 1][ar] = av.y;
    As[ac + 2][ar] = av.z;
    As[ac + 3][ar] = av.w;
    *(float4*)&Ws[wr][wc] = wv;
    __syncthreads();
#pragma unroll
    for (int kk = 0; kk < 8; ++kk) {
      const float4 a0 = *(const float4*)&As[kk][ty * 4];
      const float4 a1 = *(const float4*)&As[kk][64 + ty * 4];
      const float4 b0 = *(const float4*)&Ws[kk][tx * 4];
      const float4 b1 = *(const float4*)&Ws[kk][64 + tx * 4];
      const float ai[8] = {a0.x, a0.y, a0.z, a0.w, a1.x, a1.y, a1.z, a1.w};
      const float bj[8] = {b0.x, b0.y, b0.z, b0.w, b1.x, b1.y, b1.z, b1.w};
#pragma unroll
      for (int ii = 0; ii < 8; ++ii)
#pragma unroll
        for (int jj = 0; jj < 8; ++jj)
          acc[ii][jj] = fmaf(ai[ii], bj[jj], acc[ii][jj]);
    }
  }

#pragma unroll
  for (int ih = 0; ih < 2; ++ih)
#pragma unroll
    for (int ii = 0; ii < 4; ++ii) {
      const int r = bm + ih * 64 + ty * 4 + ii;
#pragma unroll
      for (int jh = 0; jh < 2; ++jh) {
        const int c = bn + jh * 64 + tx * 4;
        float4 ov;
        ov.x = acc[ih * 4 + ii][jh * 4 + 0];
        ov.y = acc[ih * 4 + ii][jh * 4 + 1];
        ov.z = acc[ih * 4 + ii][jh * 4 + 2];
        ov.w = acc[ih * 4 + ii][jh * 4 + 3];
        if (bias) {
          ov.x += bias[c + 0]; ov.y += bias[c + 1];
          ov.z += bias[c + 2]; ov.w += bias[c + 3];
        }
        float* cp = C + (size_t)r * N + c;
        if (ACC) {
          const float4 cv = *(const float4*)cp;
          ov.x += cv.x; ov.y += cv.y; ov.z += cv.z; ov.w += cv.w;
        }
        if (RELU) {
          ov.x = fmaxf(ov.x, 0.f); ov.y = fmaxf(ov.y, 0.f);
          ov.z = fmaxf(ov.z, 0.f); ov.w = fmaxf(ov.w, 0.f);
        }
        *(float4*)cp = ov;
      }
    }
}

static inline void launch_gemm(const float* A, const float* W, const float* bias,
                               float* C, int M, int N, int K,
                               bool relu, bool accum, hipStream_t s) {
  dim3 grid(N / 128, M / 128), blk(256);
  if (relu)       gemm_f32<1, 0><<<grid, blk, 0, s>>>(A, W, bias, C, M, N, K);
  else if (accum) gemm_f32<0, 1><<<grid, blk, 0, s>>>(A, W, bias, C, M, N, K);
  else            gemm_f32<0, 0><<<grid, blk, 0, s>>>(A, W, bias, C, M, N, K);
}

// ---------------- fused attention: one block per (b, h, query-row) ----------------
// q,k,v,out layout: [b*S + s][h*HDm + d] (heads concatenated in D)
__global__ __launch_bounds__(256) void attn_kernel(const float* __restrict__ q,
                                                   const float* __restrict__ k,
                                                   const float* __restrict__ v,
                                                   const int* __restrict__ qids,
                                                   float* __restrict__ out,
                                                   int causal) {
  const int i  = blockIdx.x % SQl;
  const int bh = blockIdx.x / SQl;
  const int h  = bh % NH;
  const int b  = bh / NH;
  const int tid = threadIdx.x;

  __shared__ float qsh[HDm];
  __shared__ float p[256];
  __shared__ float red[256];

  if (tid < HDm) qsh[tid] = q[((size_t)(b * SQl + i)) * DD + h * HDm + tid];
  __syncthreads();

  float s = -1e30f;
  if (tid < SKV) {
    bool masked = false;
    if (causal) masked = (tid > i) || (qids[b * SQl + tid] == 0);
    if (!masked) {
      const float* kr = &k[((size_t)(b * SKV + tid)) * DD + h * HDm];
      float a = 0.f;
#pragma unroll
      for (int d0 = 0; d0 < HDm; d0 += 4) {
        const float4 kv = *(const float4*)&kr[d0];
        a += qsh[d0] * kv.x + qsh[d0 + 1] * kv.y + qsh[d0 + 2] * kv.z + qsh[d0 + 3] * kv.w;
      }
      s = a * 0.125f;   // 1/sqrt(64)
    }
  }
  red[tid] = s;
  __syncthreads();
  for (int st = 128; st > 0; st >>= 1) {
    if (tid < st) red[tid] = fmaxf(red[tid], red[tid + st]);
    __syncthreads();
  }
  const float m = red[0];
  __syncthreads();
  const float e = expf(s - m);   // masked rows: expf(-huge) == 0
  red[tid] = e;
  __syncthreads();
  for (int st = 128; st > 0; st >>= 1) {
    if (tid < st) red[tid] += red[tid + st];
    __syncthreads();
  }
  const float rinv = 1.0f / red[0];
  p[tid] = e * rinv;
  __syncthreads();

  const int d = tid & 63;
  const int g = tid >> 6;   // 0..3
  float a = 0.f;
  for (int j = g; j < SKV; j += 4)
    a += p[j] * v[((size_t)(b * SKV + j)) * DD + h * HDm + d];
  red[tid] = a;
  __syncthreads();
  if (tid < 64)
    out[((size_t)(b * SQl + i)) * DD + h * HDm + d] =
        red[d] + red[64 + d] + red[128 + d] + red[192 + d];
}

// ---------------- driver ----------------
extern "C" void kernel_launch(void* const* d_in, const int* in_sizes, int n_in,
                              void* d_out, int out_size, void* d_ws, size_t ws_size,
                              hipStream_t stream) {
  (void)in_sizes; (void)n_in; (void)out_size; (void)ws_size;

  const int*   qids  = (const int*)  d_in[0];
  const float* key   = (const float*)d_in[1];
  const float* value = (const float*)d_in[2];
  const float* emb   = (const float*)d_in[3];
  const float* ln1_g = (const float*)d_in[4];
  const float* ln2_g = (const float*)d_in[5];
  const float* ln3_g = (const float*)d_in[6];
  const float* ln1_b = (const float*)d_in[7];
  const float* ln2_b = (const float*)d_in[8];
  const float* ln3_b = (const float*)d_in[9];
  const float* Wq_s  = (const float*)d_in[10];
  const float* Wk_s  = (const float*)d_in[11];
  const float* Wv_s  = (const float*)d_in[12];
  const float* Wo_s  = (const float*)d_in[13];
  const float* Wq_c  = (const float*)d_in[14];
  const float* Wk_c  = (const float*)d_in[15];
  const float* Wv_c  = (const float*)d_in[16];
  const float* Wo_c  = (const float*)d_in[17];
  const float* bq_s  = (const float*)d_in[18];
  const float* bk_s  = (const float*)d_in[19];
  const float* bv_s  = (const float*)d_in[20];
  const float* bq_c  = (const float*)d_in[21];
  const float* bk_c  = (const float*)d_in[22];
  const float* bv_c  = (const float*)d_in[23];
  const float* W1    = (const float*)d_in[24];
  const float* bf1   = (const float*)d_in[25];
  const float* W2    = (const float*)d_in[26];
  const float* bf2   = (const float*)d_in[27];
  const float* lnf_g = (const float*)d_in[28];
  const float* lnf_b = (const float*)d_in[29];

  const size_t NTOK = (size_t)BB * SQl * DD;   // 6,553,600 floats
  float* o  = (float*)d_ws;
  float* t0 = o  + NTOK;
  float* t1 = t0 + NTOK;
  float* t2 = t1 + NTOK;
  float* t3 = t2 + NTOK;
  float* fb = t3 + NTOK;                        // 6400 x 2048

  const int M = BB * SQl;                       // 6400

  embed_pe_kernel<<<(BB * SQl * DD) / 256, 256, 0, stream>>>(qids, emb, o);

  for (int l = 0; l < NL; ++l) {
    const size_t oDD = (size_t)l * DD * DD;

    // ---- self-attention ----
    ln_kernel<<<M, 256, 0, stream>>>(o, ln1_g + l * DD, ln1_b + l * DD, t0);
    launch_gemm(t0, Wq_s + oDD, bq_s + l * DD, t1, M, DD, DD, false, false, stream);
    launch_gemm(t0, Wk_s + oDD, bk_s + l * DD, t2, M, DD, DD, false, false, stream);
    launch_gemm(t0, Wv_s + oDD, bv_s + l * DD, t3, M, DD, DD, false, false, stream);
    attn_kernel<<<BB * NH * SQl, 256, 0, stream>>>(t1, t2, t3, qids, t0, 1);
    launch_gemm(t0, Wo_s + oDD, nullptr, o, M, DD, DD, false, true, stream);

    // ---- cross-attention ----
    ln_kernel<<<M, 256, 0, stream>>>(o, ln2_g + l * DD, ln2_b + l * DD, t0);
    launch_gemm(t0,    Wq_c + oDD, bq_c + l * DD, t1, M, DD, DD, false, false, stream);
    launch_gemm(key,   Wk_c + oDD, bk_c + l * DD, t2, M, DD, DD, false, false, stream);
    launch_gemm(value, Wv_c + oDD, bv_c + l * DD, t3, M, DD, DD, false, false, stream);
    attn_kernel<<<BB * NH * SQl, 256, 0, stream>>>(t1, t2, t3, nullptr, t0, 0);
    launch_gemm(t0, Wo_c + oDD, nullptr, o, M, DD, DD, false, true, stream);

    // ---- feed-forward ----
    ln_kernel<<<M, 256, 0, stream>>>(o, ln3_g + l * DD, ln3_b + l * DD, t0);
    launch_gemm(t0, W1 + (size_t)l * DD * FFD, bf1 + l * FFD, fb, M, FFD, DD, true,  false, stream);
    launch_gemm(fb, W2 + (size_t)l * FFD * DD, bf2 + l * DD,  o,  M, DD, FFD, false, true,  stream);
  }

  ln_kernel<<<M, 256, 0, stream>>>(o, lnf_g, lnf_b, (float*)d_out);
}

// Round 2
// 17248.947 us; speedup vs baseline: 1.5245x; 1.5245x over previous
//
#include <hip/hip_runtime.h>
#include <math.h>

#define BB  32
#define SQl 200
#define SKV 200
#define DD  1024
#define NH  16
#define HDm 64
#define NL  6
#define FFD 2048

// ---------------- embedding + sinusoidal positional encoding ----------------
__global__ __launch_bounds__(256) void embed_pe_kernel(const int* __restrict__ qids,
                                                       const float* __restrict__ emb,
                                                       float* __restrict__ x) {
  int idx = blockIdx.x * 256 + threadIdx.x;   // over BB*SQl*DD = 6,553,600
  int d   = idx & (DD - 1);
  int row = idx >> 10;                        // DD = 1024
  int s   = row % SQl;
  int tok = qids[row];
  float expo = (float)(d & ~1) * (1.0f / (float)DD);
  float dv   = powf(10000.0f, expo);
  float ang  = (float)s / dv;
  float pe   = (d & 1) ? cosf(ang) : sinf(ang);
  x[idx] = emb[(size_t)tok * DD + d] + pe;
}

// ---------------- LayerNorm: one block (256 threads) per row of 1024 ----------------
__global__ __launch_bounds__(256) void ln_kernel(const float* __restrict__ in,
                                                 const float* __restrict__ gam,
                                                 const float* __restrict__ bet,
                                                 float* __restrict__ out) {
  const int row = blockIdx.x;
  const int tid = threadIdx.x;
  const float4 xv = *(const float4*)&in[(size_t)row * DD + tid * 4];
  float s  = xv.x + xv.y + xv.z + xv.w;
  float sq = xv.x * xv.x + xv.y * xv.y + xv.z * xv.z + xv.w * xv.w;

  __shared__ float rs[256];
  __shared__ float rq[256];
  rs[tid] = s; rq[tid] = sq;
  __syncthreads();
  for (int st = 128; st > 0; st >>= 1) {
    if (tid < st) { rs[tid] += rs[tid + st]; rq[tid] += rq[tid + st]; }
    __syncthreads();
  }
  const float m   = rs[0] * (1.0f / (float)DD);
  const float var = rq[0] * (1.0f / (float)DD) - m * m;
  const float inv = rsqrtf(var + 1e-9f);

  float4 ov;
  const int c = tid * 4;
  ov.x = (xv.x - m) * inv * gam[c + 0] + bet[c + 0];
  ov.y = (xv.y - m) * inv * gam[c + 1] + bet[c + 1];
  ov.z = (xv.z - m) * inv * gam[c + 2] + bet[c + 2];
  ov.w = (xv.w - m) * inv * gam[c + 3] + bet[c + 3];
  *(float4*)&out[(size_t)row * DD + c] = ov;
}

// ---------------- f32 tiled GEMM: C[M,N] (+)= A[M,K] @ W[K,N] + bias ----------------
// 128x128 tile, BK=8, 256 threads, 8x8 micro-tile per thread.
template <int RELU, int ACC>
__global__ __launch_bounds__(256) void gemm_f32(const float* __restrict__ A,
                                                const float* __restrict__ W,
                                                const float* __restrict__ bias,
                                                float* __restrict__ C,
                                                int M, int N, int K) {
  __shared__ float As[8][128];   // [k][m]
  __shared__ float Ws[8][128];   // [k][n]
  const int tid = threadIdx.x;
  const int bn  = blockIdx.x * 128;
  const int bm  = blockIdx.y * 128;
  const int tx  = tid & 15;
  const int ty  = tid >> 4;
  const int ar  = tid >> 1;            // 0..127 (A tile row)
  const int ac  = (tid & 1) * 4;       // 0 or 4 (A tile k-offset)
  const int wr  = tid >> 5;            // 0..7  (W tile k-row)
  const int wc  = (tid & 31) * 4;      // 0..124 (W tile col)

  float acc[8][8] = {};

  const float* Aptr = A + (size_t)(bm + ar) * K + ac;
  const float* Wptr = W + (size_t)wr * N + bn + wc;

  for (int k0 = 0; k0 < K; k0 += 8) {
    const float4 av = *(const float4*)(Aptr + k0);
    const float4 wv = *(const float4*)(Wptr + (size_t)k0 * N);
    __syncthreads();   // previous iteration's LDS reads done
    As[ac + 0][ar] = av.x;
    As[ac + 1][ar] = av.y;
    As[ac + 2][ar] = av.z;
    As[ac + 3][ar] = av.w;
    *(float4*)&Ws[wr][wc] = wv;
    __syncthreads();
#pragma unroll
    for (int kk = 0; kk < 8; ++kk) {
      const float4 a0 = *(const float4*)&As[kk][ty * 4];
      const float4 a1 = *(const float4*)&As[kk][64 + ty * 4];
      const float4 b0 = *(const float4*)&Ws[kk][tx * 4];
      const float4 b1 = *(const float4*)&Ws[kk][64 + tx * 4];
      const float ai[8] = {a0.x, a0.y, a0.z, a0.w, a1.x, a1.y, a1.z, a1.w};
      const float bj[8] = {b0.x, b0.y, b0.z, b0.w, b1.x, b1.y, b1.z, b1.w};
#pragma unroll
      for (int ii = 0; ii < 8; ++ii)
#pragma unroll
        for (int jj = 0; jj < 8; ++jj)
          acc[ii][jj] = fmaf(ai[ii], bj[jj], acc[ii][jj]);
    }
  }

#pragma unroll
  for (int ih = 0; ih < 2; ++ih)
#pragma unroll
    for (int ii = 0; ii < 4; ++ii) {
      const int r = bm + ih * 64 + ty * 4 + ii;
#pragma unroll
      for (int jh = 0; jh < 2; ++jh) {
        const int c = bn + jh * 64 + tx * 4;
        float4 ov;
        ov.x = acc[ih * 4 + ii][jh * 4 + 0];
        ov.y = acc[ih * 4 + ii][jh * 4 + 1];
        ov.z = acc[ih * 4 + ii][jh * 4 + 2];
        ov.w = acc[ih * 4 + ii][jh * 4 + 3];
        if (bias) {
          ov.x += bias[c + 0]; ov.y += bias[c + 1];
          ov.z += bias[c + 2]; ov.w += bias[c + 3];
        }
        float* cp = C + (size_t)r * N + c;
        if (ACC) {
          const float4 cv = *(const float4*)cp;
          ov.x += cv.x; ov.y += cv.y; ov.z += cv.z; ov.w += cv.w;
        }
        if (RELU) {
          ov.x = fmaxf(ov.x, 0.f); ov.y = fmaxf(ov.y, 0.f);
          ov.z = fmaxf(ov.z, 0.f); ov.w = fmaxf(ov.w, 0.f);
        }
        *(float4*)cp = ov;
      }
    }
}

static inline void launch_gemm(const float* A, const float* W, const float* bias,
                               float* C, int M, int N, int K,
                               bool relu, bool accum, hipStream_t s) {
  dim3 grid(N / 128, M / 128), blk(256);
  if (relu)       gemm_f32<1, 0><<<grid, blk, 0, s>>>(A, W, bias, C, M, N, K);
  else if (accum) gemm_f32<0, 1><<<grid, blk, 0, s>>>(A, W, bias, C, M, N, K);
  else            gemm_f32<0, 0><<<grid, blk, 0, s>>>(A, W, bias, C, M, N, K);
}

// ---------------- flash attention: one block per (b, h), lane = q-row ----------------
// K[j][*] and V[j][*] are wave-uniform -> scalar (s_load) operands on the
// scalar pipe; inner loop is pure VALU (128 v_fma per j). Q and O live in
// registers (64+64 VGPRs). Online softmax with defer-max threshold 8 (T13).
template <int CAUSAL>
__global__ __launch_bounds__(256) void flash_attn_kernel(const float* __restrict__ q,
                                                         const float* __restrict__ k,
                                                         const float* __restrict__ v,
                                                         const int* __restrict__ qids,
                                                         float* __restrict__ out) {
  const int bh   = blockIdx.x;
  const int h    = bh & (NH - 1);
  const int b    = bh / NH;
  const int tid  = threadIdx.x;
  const int wv   = tid >> 6;
  const int lane = tid & 63;
  const int i    = wv * 64 + lane;          // q row handled by this lane (0..255)
  const bool act = (i < SQl);
  const int  qi  = act ? i : 0;

  __shared__ float osh[4][64][65];          // per-wave transpose buffer (66.6 KB)

  // Q row -> registers (one-time strided gather; L1-absorbed)
  const float* qp = q + ((size_t)(b * SQl + qi)) * DD + h * HDm;
  float qr[64];
#pragma unroll
  for (int d = 0; d < 64; ++d) qr[d] = qp[d];

  float acc[64];
#pragma unroll
  for (int d = 0; d < 64; ++d) acc[d] = 0.f;
  float m = -1e30f, l = 0.f;

  for (int j = 0; j < SKV; ++j) {
    if (CAUSAL) {
      if (qids[b * SQl + j] == 0) continue;          // block-uniform skip
    }
    const float* kp = k + ((size_t)(b * SKV + j)) * DD + h * HDm;  // uniform -> s_load
    float s0 = 0.f, s1 = 0.f, s2 = 0.f, s3 = 0.f;
#pragma unroll
    for (int d = 0; d < 64; d += 4) {
      s0 = fmaf(qr[d + 0], kp[d + 0], s0);
      s1 = fmaf(qr[d + 1], kp[d + 1], s1);
      s2 = fmaf(qr[d + 2], kp[d + 2], s2);
      s3 = fmaf(qr[d + 3], kp[d + 3], s3);
    }
    float s = ((s0 + s1) + (s2 + s3)) * 0.125f;      // 1/sqrt(64)
    if (CAUSAL) {
      if (j > i) s = -1e38f;                          // causal mask (per-lane)
    }
    if (__any(s > m + 8.f)) {                         // defer-max rescale (rare)
      const float mn = fmaxf(m, s);
      const float sc = __expf(m - mn);
      l *= sc;
#pragma unroll
      for (int d = 0; d < 64; ++d) acc[d] *= sc;
      m = mn;
    }
    const float p = __expf(s - m);                    // bounded by e^8
    l += p;
    const float* vp = v + ((size_t)(b * SKV + j)) * DD + h * HDm;  // uniform -> s_load
#pragma unroll
    for (int d = 0; d < 64; ++d) acc[d] = fmaf(p, vp[d], acc[d]);
  }

  const float linv = 1.0f / l;
#pragma unroll
  for (int d = 0; d < 64; ++d) osh[wv][lane][d] = acc[d] * linv;
  __syncthreads();

  // coalesced store: lane sweeps d, rows sweep LDS
  const int rbase = wv * 64;
#pragma unroll 1
  for (int r = 0; r < 64; ++r) {
    const int row = rbase + r;
    if (row < SQl)
      out[((size_t)(b * SQl + row)) * DD + h * HDm + lane] = osh[wv][r][lane];
  }
}

// ---------------- driver ----------------
extern "C" void kernel_launch(void* const* d_in, const int* in_sizes, int n_in,
                              void* d_out, int out_size, void* d_ws, size_t ws_size,
                              hipStream_t stream) {
  (void)in_sizes; (void)n_in; (void)out_size; (void)ws_size;

  const int*   qids  = (const int*)  d_in[0];
  const float* key   = (const float*)d_in[1];
  const float* value = (const float*)d_in[2];
  const float* emb   = (const float*)d_in[3];
  const float* ln1_g = (const float*)d_in[4];
  const float* ln2_g = (const float*)d_in[5];
  const float* ln3_g = (const float*)d_in[6];
  const float* ln1_b = (const float*)d_in[7];
  const float* ln2_b = (const float*)d_in[8];
  const float* ln3_b = (const float*)d_in[9];
  const float* Wq_s  = (const float*)d_in[10];
  const float* Wk_s  = (const float*)d_in[11];
  const float* Wv_s  = (const float*)d_in[12];
  const float* Wo_s  = (const float*)d_in[13];
  const float* Wq_c  = (const float*)d_in[14];
  const float* Wk_c  = (const float*)d_in[15];
  const float* Wv_c  = (const float*)d_in[16];
  const float* Wo_c  = (const float*)d_in[17];
  const float* bq_s  = (const float*)d_in[18];
  const float* bk_s  = (const float*)d_in[19];
  const float* bv_s  = (const float*)d_in[20];
  const float* bq_c  = (const float*)d_in[21];
  const float* bk_c  = (const float*)d_in[22];
  const float* bv_c  = (const float*)d_in[23];
  const float* W1    = (const float*)d_in[24];
  const float* bf1   = (const float*)d_in[25];
  const float* W2    = (const float*)d_in[26];
  const float* bf2   = (const float*)d_in[27];
  const float* lnf_g = (const float*)d_in[28];
  const float* lnf_b = (const float*)d_in[29];

  const size_t NTOK = (size_t)BB * SQl * DD;   // 6,553,600 floats
  float* o  = (float*)d_ws;
  float* t0 = o  + NTOK;
  float* t1 = t0 + NTOK;
  float* t2 = t1 + NTOK;
  float* t3 = t2 + NTOK;
  float* fb = t3 + NTOK;                        // 6400 x 2048

  const int M = BB * SQl;                       // 6400

  embed_pe_kernel<<<(BB * SQl * DD) / 256, 256, 0, stream>>>(qids, emb, o);

  for (int l = 0; l < NL; ++l) {
    const size_t oDD = (size_t)l * DD * DD;

    // ---- self-attention ----
    ln_kernel<<<M, 256, 0, stream>>>(o, ln1_g + l * DD, ln1_b + l * DD, t0);
    launch_gemm(t0, Wq_s + oDD, bq_s + l * DD, t1, M, DD, DD, false, false, stream);
    launch_gemm(t0, Wk_s + oDD, bk_s + l * DD, t2, M, DD, DD, false, false, stream);
    launch_gemm(t0, Wv_s + oDD, bv_s + l * DD, t3, M, DD, DD, false, false, stream);
    flash_attn_kernel<1><<<BB * NH, 256, 0, stream>>>(t1, t2, t3, qids, t0);
    launch_gemm(t0, Wo_s + oDD, nullptr, o, M, DD, DD, false, true, stream);

    // ---- cross-attention ----
    ln_kernel<<<M, 256, 0, stream>>>(o, ln2_g + l * DD, ln2_b + l * DD, t0);
    launch_gemm(t0,    Wq_c + oDD, bq_c + l * DD, t1, M, DD, DD, false, false, stream);
    launch_gemm(key,   Wk_c + oDD, bk_c + l * DD, t2, M, DD, DD, false, false, stream);
    launch_gemm(value, Wv_c + oDD, bv_c + l * DD, t3, M, DD, DD, false, false, stream);
    flash_attn_kernel<0><<<BB * NH, 256, 0, stream>>>(t1, t2, t3, nullptr, t0);
    launch_gemm(t0, Wo_c + oDD, nullptr, o, M, DD, DD, false, true, stream);

    // ---- feed-forward ----
    ln_kernel<<<M, 256, 0, stream>>>(o, ln3_g + l * DD, ln3_b + l * DD, t0);
    launch_gemm(t0, W1 + (size_t)l * DD * FFD, bf1 + l * FFD, fb, M, FFD, DD, true,  false, stream);
    launch_gemm(fb, W2 + (size_t)l * FFD * DD, bf2 + l * DD,  o,  M, DD, FFD, false, true,  stream);
  }

  ln_kernel<<<M, 256, 0, stream>>>(o, lnf_g, lnf_b, (float*)d_out);
}

// Round 3
// 6573.866 us; speedup vs baseline: 4.0000x; 2.6239x over previous
//
#include <hip/hip_runtime.h>
#include <math.h>

#define BB  32
#define SQl 200
#define SKV 200
#define DD  1024
#define NH  16
#define HDm 64
#define NL  6
#define FFD 2048

typedef __attribute__((ext_vector_type(8))) short  short8v;
typedef __attribute__((ext_vector_type(4))) float  floatx4;

// float -> bf16 bits, round-to-nearest-even (values are finite here)
__device__ __forceinline__ ushort f2bf(float x) {
  uint u = __builtin_bit_cast(uint, x);
  u = (u + 0x7FFFu + ((u >> 16) & 1u)) >> 16;
  return (ushort)u;
}

__device__ __forceinline__ void gll16(const void* g, void* l) {
  __builtin_amdgcn_global_load_lds((const __attribute__((address_space(1))) void*)g,
                                   (__attribute__((address_space(3))) void*)l,
                                   16, 0, 0);
}

// ---------------- embedding + sinusoidal positional encoding ----------------
__global__ __launch_bounds__(256) void embed_pe_kernel(const int* __restrict__ qids,
                                                       const float* __restrict__ emb,
                                                       float* __restrict__ x) {
  int idx = blockIdx.x * 256 + threadIdx.x;
  int d   = idx & (DD - 1);
  int row = idx >> 10;
  int s   = row % SQl;
  int tok = qids[row];
  float expo = (float)(d & ~1) * (1.0f / (float)DD);
  float dv   = powf(10000.0f, expo);
  float ang  = (float)s / dv;
  float pe   = (d & 1) ? cosf(ang) : sinf(ang);
  x[idx] = emb[(size_t)tok * DD + d] + pe;
}

// ---------------- f32 -> bf16 elementwise (8 elems/thread) ----------------
__global__ __launch_bounds__(256) void cvt_bf16_kernel(const float* __restrict__ in,
                                                       ushort* __restrict__ out, int n8) {
  int idx = blockIdx.x * 256 + threadIdx.x;
  if (idx >= n8) return;
  const floatx4 va = ((const floatx4*)in)[idx * 2];
  const floatx4 vb = ((const floatx4*)in)[idx * 2 + 1];
  short8v o;
  o[0] = (short)f2bf(va.x); o[1] = (short)f2bf(va.y);
  o[2] = (short)f2bf(va.z); o[3] = (short)f2bf(va.w);
  o[4] = (short)f2bf(vb.x); o[5] = (short)f2bf(vb.y);
  o[6] = (short)f2bf(vb.z); o[7] = (short)f2bf(vb.w);
  ((short8v*)out)[idx] = o;
}

// ---------------- batched transpose: W[K][N] f32 -> WT[N][K] bf16 ----------------
struct P8 { const float* p[8]; };
__global__ __launch_bounds__(256) void transpose_bf16_kernel(P8 srcs, ushort* __restrict__ dst,
                                                             int K, int N) {
  __shared__ float t[32][33];
  const int z = blockIdx.z;
  const float* __restrict__ W = srcs.p[z];
  ushort* __restrict__ WT = dst + (size_t)z * K * N;
  const int n0 = blockIdx.x * 32, k0 = blockIdx.y * 32;
  const int tx = threadIdx.x & 31, ty = threadIdx.x >> 5;   // ty 0..7
#pragma unroll
  for (int i = 0; i < 4; ++i)
    t[ty + i * 8][tx] = W[(size_t)(k0 + ty + i * 8) * N + n0 + tx];
  __syncthreads();
#pragma unroll
  for (int i = 0; i < 4; ++i)
    WT[(size_t)(n0 + ty + i * 8) * K + k0 + tx] = f2bf(t[tx][ty + i * 8]);
}

// ---------------- LayerNorm (f32 in; bf16 or f32 out) ----------------
template <int OBF16>
__global__ __launch_bounds__(256) void ln_kernel(const float* __restrict__ in,
                                                 const float* __restrict__ gam,
                                                 const float* __restrict__ bet,
                                                 float* __restrict__ outf,
                                                 ushort* __restrict__ outb) {
  const int row = blockIdx.x;
  const int tid = threadIdx.x;
  const float4 xv = *(const float4*)&in[(size_t)row * DD + tid * 4];
  float s  = xv.x + xv.y + xv.z + xv.w;
  float sq = xv.x * xv.x + xv.y * xv.y + xv.z * xv.z + xv.w * xv.w;

  __shared__ float rs[256];
  __shared__ float rq[256];
  rs[tid] = s; rq[tid] = sq;
  __syncthreads();
  for (int st = 128; st > 0; st >>= 1) {
    if (tid < st) { rs[tid] += rs[tid + st]; rq[tid] += rq[tid + st]; }
    __syncthreads();
  }
  const float m   = rs[0] * (1.0f / (float)DD);
  const float var = rq[0] * (1.0f / (float)DD) - m * m;
  const float inv = rsqrtf(var + 1e-9f);

  const int c = tid * 4;
  float o0 = (xv.x - m) * inv * gam[c + 0] + bet[c + 0];
  float o1 = (xv.y - m) * inv * gam[c + 1] + bet[c + 1];
  float o2 = (xv.z - m) * inv * gam[c + 2] + bet[c + 2];
  float o3 = (xv.w - m) * inv * gam[c + 3] + bet[c + 3];
  if (OBF16) {
    uint2 pk;
    pk.x = (uint)f2bf(o0) | ((uint)f2bf(o1) << 16);
    pk.y = (uint)f2bf(o2) | ((uint)f2bf(o3) << 16);
    *(uint2*)&outb[(size_t)row * DD + c] = pk;
  } else {
    float4 ov; ov.x = o0; ov.y = o1; ov.z = o2; ov.w = o3;
    *(float4*)&outf[(size_t)row * DD + c] = ov;
  }
}

// ---------------- bf16 MFMA GEMM: C[M,N] (+)= A[M,K] @ BT[N,K]^T + bias ----------------
// 128x128 tile, BK=32, 4 waves (2x2), 64x64 per wave, mfma_f32_16x16x32_bf16.
// LDS layout: 512 slots of 16B per operand; slot s holds row m=s>>2, k-group
// kg=(s&3)^((m>>1)&3)  (XOR swizzle -> conflict-free ds_read_b128, staged via
// pre-swizzled global source with linear global_load_lds dest).
template <int RELU, int ACC, int OBF16>
__global__ __launch_bounds__(256) void gemm_mfma(const ushort* __restrict__ A,
                                                 const ushort* __restrict__ BT,
                                                 const float* __restrict__ bias,
                                                 float* __restrict__ C,
                                                 ushort* __restrict__ Cb,
                                                 int M, int N, int K) {
  __shared__ short8v As[512];   // 8 KB
  __shared__ short8v Bs[512];   // 8 KB
  const int tid  = threadIdx.x;
  const int wid  = tid >> 6;
  const int lane = tid & 63;
  const int bm = blockIdx.y * 128;
  const int bn = blockIdx.x * 128;
  const int wm = (wid >> 1) * 64;
  const int wn = (wid & 1) * 64;
  const int lq = lane & 15;
  const int lg = lane >> 4;

  // staging: wave stages slots [wid*64, wid*64+64) and +256
  const int s0  = wid * 64 + lane;
  const int s1  = s0 + 256;
  const int m0s = s0 >> 2, kg0 = (s0 & 3) ^ ((m0s >> 1) & 3);
  const int m1s = s1 >> 2, kg1 = (s1 & 3) ^ ((m1s >> 1) & 3);

  const ushort* a0 = A  + (size_t)(bm + m0s) * K + kg0 * 8;
  const ushort* a1 = A  + (size_t)(bm + m1s) * K + kg1 * 8;
  const ushort* b0 = BT + (size_t)(bn + m0s) * K + kg0 * 8;
  const ushort* b1 = BT + (size_t)(bn + m1s) * K + kg1 * 8;

  short8v* As0 = &As[wid * 64];
  short8v* As1 = &As[256 + wid * 64];
  short8v* Bs0 = &Bs[wid * 64];
  short8v* Bs1 = &Bs[256 + wid * 64];

  int aslot[4], bslot[4];
#pragma unroll
  for (int i = 0; i < 4; ++i) {
    const int mr = wm + i * 16 + lq;
    aslot[i] = mr * 4 + (lg ^ ((mr >> 1) & 3));
    const int nr = wn + i * 16 + lq;
    bslot[i] = nr * 4 + (lg ^ ((nr >> 1) & 3));
  }

  floatx4 acc[4][4];
  const floatx4 fz = {0.f, 0.f, 0.f, 0.f};
#pragma unroll
  for (int mi = 0; mi < 4; ++mi)
#pragma unroll
    for (int ni = 0; ni < 4; ++ni) acc[mi][ni] = fz;

  for (int k0 = 0; k0 < K; k0 += 32) {
    gll16(a0 + k0, As0);
    gll16(a1 + k0, As1);
    gll16(b0 + k0, Bs0);
    gll16(b1 + k0, Bs1);
    __syncthreads();                       // vmcnt(0) drain + barrier
    short8v af[4], bf_[4];
#pragma unroll
    for (int i = 0; i < 4; ++i) { af[i] = As[aslot[i]]; bf_[i] = Bs[bslot[i]]; }
#pragma unroll
    for (int mi = 0; mi < 4; ++mi)
#pragma unroll
      for (int ni = 0; ni < 4; ++ni)
        acc[mi][ni] = __builtin_amdgcn_mfma_f32_16x16x32_bf16(af[mi], bf_[ni], acc[mi][ni], 0, 0, 0);
    __syncthreads();                       // reads done before next overwrite
  }

  // epilogue: C/D layout col = lane&15, row = (lane>>4)*4 + reg
#pragma unroll
  for (int mi = 0; mi < 4; ++mi) {
    const int row = bm + wm + mi * 16 + lg * 4;
#pragma unroll
    for (int ni = 0; ni < 4; ++ni) {
      const int col = bn + wn + ni * 16 + lq;
      const float bv = bias ? bias[col] : 0.f;
#pragma unroll
      for (int r = 0; r < 4; ++r) {
        float val = acc[mi][ni][r] + bv;
        if (ACC)  val += C[(size_t)(row + r) * N + col];
        if (RELU) val = fmaxf(val, 0.f);
        if (OBF16) Cb[(size_t)(row + r) * N + col] = f2bf(val);
        else       C [(size_t)(row + r) * N + col] = val;
      }
    }
  }
}

static inline void launch_g(const ushort* A, const ushort* BT, const float* bias,
                            float* C, ushort* Cb, int M, int N, int K,
                            int mode, hipStream_t s) {
  dim3 grid(N / 128, M / 128), blk(256);
  if (mode == 0)      gemm_mfma<0, 0, 0><<<grid, blk, 0, s>>>(A, BT, bias, C, Cb, M, N, K);
  else if (mode == 1) gemm_mfma<0, 1, 0><<<grid, blk, 0, s>>>(A, BT, bias, C, Cb, M, N, K);
  else                gemm_mfma<1, 0, 1><<<grid, blk, 0, s>>>(A, BT, bias, C, Cb, M, N, K);
}

// ---------------- flash attention: one block per (b, h), lane = q-row ----------------
// K/V rows are wave-uniform -> scalar loads; inner loop pure VALU. bf16 output
// straight from registers (no LDS -> 3 waves/SIMD occupancy).
template <int CAUSAL>
__global__ __launch_bounds__(256, 3) void flash_attn_kernel(const float* __restrict__ q,
                                                            const float* __restrict__ k,
                                                            const float* __restrict__ v,
                                                            const int* __restrict__ qids,
                                                            ushort* __restrict__ out) {
  const int bh   = blockIdx.x;
  const int h    = bh & (NH - 1);
  const int b    = bh / NH;
  const int tid  = threadIdx.x;
  const int wv   = tid >> 6;
  const int lane = tid & 63;
  const int i    = wv * 64 + lane;
  const bool act = (i < SQl);
  const int  qi  = act ? i : 0;

  const float* qp = q + ((size_t)(b * SQl + qi)) * DD + h * HDm;
  float qr[64];
#pragma unroll
  for (int d = 0; d < 64; ++d) qr[d] = qp[d];

  float acc[64];
#pragma unroll
  for (int d = 0; d < 64; ++d) acc[d] = 0.f;
  float m = -1e30f, l = 0.f;

  for (int j = 0; j < SKV; ++j) {
    if (CAUSAL) {
      if (qids[b * SQl + j] == 0) continue;           // block-uniform skip
    }
    const float* kp = k + ((size_t)(b * SKV + j)) * DD + h * HDm;
    float s0 = 0.f, s1 = 0.f, s2 = 0.f, s3 = 0.f;
#pragma unroll
    for (int d = 0; d < 64; d += 4) {
      s0 = fmaf(qr[d + 0], kp[d + 0], s0);
      s1 = fmaf(qr[d + 1], kp[d + 1], s1);
      s2 = fmaf(qr[d + 2], kp[d + 2], s2);
      s3 = fmaf(qr[d + 3], kp[d + 3], s3);
    }
    float s = ((s0 + s1) + (s2 + s3)) * 0.125f;
    if (CAUSAL) {
      if (j > i) s = -1e38f;
    }
    if (__any(s > m + 8.f)) {                         // defer-max rescale (T13)
      const float mn = fmaxf(m, s);
      const float sc = __expf(m - mn);
      l *= sc;
#pragma unroll
      for (int d = 0; d < 64; ++d) acc[d] *= sc;
      m = mn;
    }
    const float p = __expf(s - m);
    l += p;
    const float* vp = v + ((size_t)(b * SKV + j)) * DD + h * HDm;
#pragma unroll
    for (int d = 0; d < 64; ++d) acc[d] = fmaf(p, vp[d], acc[d]);
  }

  if (act) {
    const float linv = 1.0f / l;
    ushort* op = out + ((size_t)(b * SQl + i)) * DD + h * HDm;
#pragma unroll
    for (int d0 = 0; d0 < 64; d0 += 8) {
      short8v o;
#pragma unroll
      for (int e = 0; e < 8; ++e) o[e] = (short)f2bf(acc[d0 + e] * linv);
      *(short8v*)(op + d0) = o;
    }
  }
}

// ---------------- driver ----------------
extern "C" void kernel_launch(void* const* d_in, const int* in_sizes, int n_in,
                              void* d_out, int out_size, void* d_ws, size_t ws_size,
                              hipStream_t stream) {
  (void)in_sizes; (void)n_in; (void)out_size; (void)ws_size;

  const int*   qids  = (const int*)  d_in[0];
  const float* key   = (const float*)d_in[1];
  const float* value = (const float*)d_in[2];
  const float* emb   = (const float*)d_in[3];
  const float* ln1_g = (const float*)d_in[4];
  const float* ln2_g = (const float*)d_in[5];
  const float* ln3_g = (const float*)d_in[6];
  const float* ln1_b = (const float*)d_in[7];
  const float* ln2_b = (const float*)d_in[8];
  const float* ln3_b = (const float*)d_in[9];
  const float* Wq_s  = (const float*)d_in[10];
  const float* Wk_s  = (const float*)d_in[11];
  const float* Wv_s  = (const float*)d_in[12];
  const float* Wo_s  = (const float*)d_in[13];
  const float* Wq_c  = (const float*)d_in[14];
  const float* Wk_c  = (const float*)d_in[15];
  const float* Wv_c  = (const float*)d_in[16];
  const float* Wo_c  = (const float*)d_in[17];
  const float* bq_s  = (const float*)d_in[18];
  const float* bk_s  = (const float*)d_in[19];
  const float* bv_s  = (const float*)d_in[20];
  const float* bq_c  = (const float*)d_in[21];
  const float* bk_c  = (const float*)d_in[22];
  const float* bv_c  = (const float*)d_in[23];
  const float* W1    = (const float*)d_in[24];
  const float* bf1   = (const float*)d_in[25];
  const float* W2    = (const float*)d_in[26];
  const float* bf2   = (const float*)d_in[27];
  const float* lnf_g = (const float*)d_in[28];
  const float* lnf_b = (const float*)d_in[29];

  const size_t NTOK = (size_t)BB * SQl * DD;   // 6,553,600
  char* w = (char*)d_ws;
  float*  o   = (float*)w;  w += NTOK * 4;
  float*  t1  = (float*)w;  w += NTOK * 4;
  float*  t2  = (float*)w;  w += NTOK * 4;
  float*  t3  = (float*)w;  w += NTOK * 4;
  ushort* t0b = (ushort*)w; w += NTOK * 2;
  ushort* kb  = (ushort*)w; w += NTOK * 2;
  ushort* vb  = (ushort*)w; w += NTOK * 2;
  ushort* wt  = (ushort*)w; w += (size_t)8 * DD * DD * 2;   // 8 transposed DxD
  ushort* wt1 = (ushort*)w; w += (size_t)DD * FFD * 2;
  ushort* wt2 = (ushort*)w; w += (size_t)FFD * DD * 2;
  ushort* fbb = (ushort*)(void*)t1;            // FF1 out aliases t1 (both 26.2 MB)

  const int M = BB * SQl;                      // 6400

  embed_pe_kernel<<<(int)(NTOK / 256), 256, 0, stream>>>(qids, emb, o);
  cvt_bf16_kernel<<<(int)(NTOK / 8 + 255) / 256, 256, 0, stream>>>(key,   kb, (int)(NTOK / 8));
  cvt_bf16_kernel<<<(int)(NTOK / 8 + 255) / 256, 256, 0, stream>>>(value, vb, (int)(NTOK / 8));

  for (int l = 0; l < NL; ++l) {
    const size_t oDD = (size_t)l * DD * DD;

    // per-layer weight transposes (f32 -> bf16, W -> W^T)
    P8 p8;
    p8.p[0] = Wq_s + oDD; p8.p[1] = Wk_s + oDD; p8.p[2] = Wv_s + oDD; p8.p[3] = Wo_s + oDD;
    p8.p[4] = Wq_c + oDD; p8.p[5] = Wk_c + oDD; p8.p[6] = Wv_c + oDD; p8.p[7] = Wo_c + oDD;
    transpose_bf16_kernel<<<dim3(DD / 32, DD / 32, 8), 256, 0, stream>>>(p8, wt, DD, DD);
    P8 p1; p1.p[0] = W1 + (size_t)l * DD * FFD;
    transpose_bf16_kernel<<<dim3(FFD / 32, DD / 32, 1), 256, 0, stream>>>(p1, wt1, DD, FFD);
    P8 p2; p2.p[0] = W2 + (size_t)l * FFD * DD;
    transpose_bf16_kernel<<<dim3(DD / 32, FFD / 32, 1), 256, 0, stream>>>(p2, wt2, FFD, DD);

    const size_t WD = (size_t)DD * DD;

    // ---- self-attention ----
    ln_kernel<1><<<M, 256, 0, stream>>>(o, ln1_g + l * DD, ln1_b + l * DD, nullptr, t0b);
    launch_g(t0b, wt + 0 * WD, bq_s + l * DD, t1, nullptr, M, DD, DD, 0, stream);
    launch_g(t0b, wt + 1 * WD, bk_s + l * DD, t2, nullptr, M, DD, DD, 0, stream);
    launch_g(t0b, wt + 2 * WD, bv_s + l * DD, t3, nullptr, M, DD, DD, 0, stream);
    flash_attn_kernel<1><<<BB * NH, 256, 0, stream>>>(t1, t2, t3, qids, t0b);
    launch_g(t0b, wt + 3 * WD, nullptr, o, nullptr, M, DD, DD, 1, stream);

    // ---- cross-attention ----
    ln_kernel<1><<<M, 256, 0, stream>>>(o, ln2_g + l * DD, ln2_b + l * DD, nullptr, t0b);
    launch_g(t0b, wt + 4 * WD, bq_c + l * DD, t1, nullptr, M, DD, DD, 0, stream);
    launch_g(kb,  wt + 5 * WD, bk_c + l * DD, t2, nullptr, M, DD, DD, 0, stream);
    launch_g(vb,  wt + 6 * WD, bv_c + l * DD, t3, nullptr, M, DD, DD, 0, stream);
    flash_attn_kernel<0><<<BB * NH, 256, 0, stream>>>(t1, t2, t3, nullptr, t0b);
    launch_g(t0b, wt + 7 * WD, nullptr, o, nullptr, M, DD, DD, 1, stream);

    // ---- feed-forward ----
    ln_kernel<1><<<M, 256, 0, stream>>>(o, ln3_g + l * DD, ln3_b + l * DD, nullptr, t0b);
    launch_g(t0b, wt1, bf1 + l * FFD, nullptr, fbb, M, FFD, DD, 2, stream);
    launch_g(fbb, wt2, bf2 + l * DD,  o, nullptr, M, DD, FFD, 1, stream);
  }

  ln_kernel<0><<<M, 256, 0, stream>>>(o, lnf_g, lnf_b, (float*)d_out, nullptr);
}

// Round 4
// 3028.088 us; speedup vs baseline: 8.6839x; 2.1710x over previous
//
#include <hip/hip_runtime.h>
#include <math.h>

#define BB  32
#define SQl 200
#define SKV 200
#define DD  1024
#define NH  16
#define HDm 64
#define NL  6
#define FFD 2048

typedef __attribute__((ext_vector_type(8))) short  short8v;
typedef __attribute__((ext_vector_type(4))) float  floatx4;

// float -> bf16 bits, round-to-nearest-even (values are finite here)
__device__ __forceinline__ ushort f2bf(float x) {
  uint u = __builtin_bit_cast(uint, x);
  u = (u + 0x7FFFu + ((u >> 16) & 1u)) >> 16;
  return (ushort)u;
}

__device__ __forceinline__ void gll16(const void* g, void* l) {
  __builtin_amdgcn_global_load_lds((const __attribute__((address_space(1))) void*)g,
                                   (__attribute__((address_space(3))) void*)l,
                                   16, 0, 0);
}

// ---------------- embedding + sinusoidal positional encoding ----------------
__global__ __launch_bounds__(256) void embed_pe_kernel(const int* __restrict__ qids,
                                                       const float* __restrict__ emb,
                                                       float* __restrict__ x) {
  int idx = blockIdx.x * 256 + threadIdx.x;
  int d   = idx & (DD - 1);
  int row = idx >> 10;
  int s   = row % SQl;
  int tok = qids[row];
  float expo = (float)(d & ~1) * (1.0f / (float)DD);
  float dv   = powf(10000.0f, expo);
  float ang  = (float)s / dv;
  float pe   = (d & 1) ? cosf(ang) : sinf(ang);
  x[idx] = emb[(size_t)tok * DD + d] + pe;
}

// ---------------- f32 -> bf16 elementwise (8 elems/thread) ----------------
__global__ __launch_bounds__(256) void cvt_bf16_kernel(const float* __restrict__ in,
                                                       ushort* __restrict__ out, int n8) {
  int idx = blockIdx.x * 256 + threadIdx.x;
  if (idx >= n8) return;
  const floatx4 va = ((const floatx4*)in)[idx * 2];
  const floatx4 vb = ((const floatx4*)in)[idx * 2 + 1];
  short8v o;
  o[0] = (short)f2bf(va.x); o[1] = (short)f2bf(va.y);
  o[2] = (short)f2bf(va.z); o[3] = (short)f2bf(va.w);
  o[4] = (short)f2bf(vb.x); o[5] = (short)f2bf(vb.y);
  o[6] = (short)f2bf(vb.z); o[7] = (short)f2bf(vb.w);
  ((short8v*)out)[idx] = o;
}

// ---------------- batched transpose: W[K][N] f32 -> WT[N][K] bf16 ----------------
struct P8 { const float* p[8]; };
__global__ __launch_bounds__(256) void transpose_bf16_kernel(P8 srcs, ushort* __restrict__ dst,
                                                             int K, int N) {
  __shared__ float t[32][33];
  const int z = blockIdx.z;
  const float* __restrict__ W = srcs.p[z];
  ushort* __restrict__ WT = dst + (size_t)z * K * N;
  const int n0 = blockIdx.x * 32, k0 = blockIdx.y * 32;
  const int tx = threadIdx.x & 31, ty = threadIdx.x >> 5;   // ty 0..7
#pragma unroll
  for (int i = 0; i < 4; ++i)
    t[ty + i * 8][tx] = W[(size_t)(k0 + ty + i * 8) * N + n0 + tx];
  __syncthreads();
#pragma unroll
  for (int i = 0; i < 4; ++i)
    WT[(size_t)(n0 + ty + i * 8) * K + k0 + tx] = f2bf(t[tx][ty + i * 8]);
}

// ---------------- LayerNorm (f32 in; bf16 or f32 out) ----------------
template <int OBF16>
__global__ __launch_bounds__(256) void ln_kernel(const float* __restrict__ in,
                                                 const float* __restrict__ gam,
                                                 const float* __restrict__ bet,
                                                 float* __restrict__ outf,
                                                 ushort* __restrict__ outb) {
  const int row = blockIdx.x;
  const int tid = threadIdx.x;
  const float4 xv = *(const float4*)&in[(size_t)row * DD + tid * 4];
  float s  = xv.x + xv.y + xv.z + xv.w;
  float sq = xv.x * xv.x + xv.y * xv.y + xv.z * xv.z + xv.w * xv.w;

  __shared__ float rs[256];
  __shared__ float rq[256];
  rs[tid] = s; rq[tid] = sq;
  __syncthreads();
  for (int st = 128; st > 0; st >>= 1) {
    if (tid < st) { rs[tid] += rs[tid + st]; rq[tid] += rq[tid + st]; }
    __syncthreads();
  }
  const float m   = rs[0] * (1.0f / (float)DD);
  const float var = rq[0] * (1.0f / (float)DD) - m * m;
  const float inv = rsqrtf(var + 1e-9f);

  const int c = tid * 4;
  float o0 = (xv.x - m) * inv * gam[c + 0] + bet[c + 0];
  float o1 = (xv.y - m) * inv * gam[c + 1] + bet[c + 1];
  float o2 = (xv.z - m) * inv * gam[c + 2] + bet[c + 2];
  float o3 = (xv.w - m) * inv * gam[c + 3] + bet[c + 3];
  if (OBF16) {
    uint2 pk;
    pk.x = (uint)f2bf(o0) | ((uint)f2bf(o1) << 16);
    pk.y = (uint)f2bf(o2) | ((uint)f2bf(o3) << 16);
    *(uint2*)&outb[(size_t)row * DD + c] = pk;
  } else {
    float4 ov; ov.x = o0; ov.y = o1; ov.z = o2; ov.w = o3;
    *(float4*)&outf[(size_t)row * DD + c] = ov;
  }
}

// ---------------- bf16 MFMA GEMM: C[M,N] (+)= A[M,K] @ BT[N,K]^T + bias ----------------
template <int RELU, int ACC, int OBF16>
__global__ __launch_bounds__(256) void gemm_mfma(const ushort* __restrict__ A,
                                                 const ushort* __restrict__ BT,
                                                 const float* __restrict__ bias,
                                                 float* __restrict__ C,
                                                 ushort* __restrict__ Cb,
                                                 int M, int N, int K) {
  __shared__ short8v As[512];   // 8 KB
  __shared__ short8v Bs[512];   // 8 KB
  const int tid  = threadIdx.x;
  const int wid  = tid >> 6;
  const int lane = tid & 63;
  const int bm = blockIdx.y * 128;
  const int bn = blockIdx.x * 128;
  const int wm = (wid >> 1) * 64;
  const int wn = (wid & 1) * 64;
  const int lq = lane & 15;
  const int lg = lane >> 4;

  const int s0  = wid * 64 + lane;
  const int s1  = s0 + 256;
  const int m0s = s0 >> 2, kg0 = (s0 & 3) ^ ((m0s >> 1) & 3);
  const int m1s = s1 >> 2, kg1 = (s1 & 3) ^ ((m1s >> 1) & 3);

  const ushort* a0 = A  + (size_t)(bm + m0s) * K + kg0 * 8;
  const ushort* a1 = A  + (size_t)(bm + m1s) * K + kg1 * 8;
  const ushort* b0 = BT + (size_t)(bn + m0s) * K + kg0 * 8;
  const ushort* b1 = BT + (size_t)(bn + m1s) * K + kg1 * 8;

  short8v* As0 = &As[wid * 64];
  short8v* As1 = &As[256 + wid * 64];
  short8v* Bs0 = &Bs[wid * 64];
  short8v* Bs1 = &Bs[256 + wid * 64];

  int aslot[4], bslot[4];
#pragma unroll
  for (int i = 0; i < 4; ++i) {
    const int mr = wm + i * 16 + lq;
    aslot[i] = mr * 4 + (lg ^ ((mr >> 1) & 3));
    const int nr = wn + i * 16 + lq;
    bslot[i] = nr * 4 + (lg ^ ((nr >> 1) & 3));
  }

  floatx4 acc[4][4];
  const floatx4 fz = {0.f, 0.f, 0.f, 0.f};
#pragma unroll
  for (int mi = 0; mi < 4; ++mi)
#pragma unroll
    for (int ni = 0; ni < 4; ++ni) acc[mi][ni] = fz;

  for (int k0 = 0; k0 < K; k0 += 32) {
    gll16(a0 + k0, As0);
    gll16(a1 + k0, As1);
    gll16(b0 + k0, Bs0);
    gll16(b1 + k0, Bs1);
    __syncthreads();
    short8v af[4], bf_[4];
#pragma unroll
    for (int i = 0; i < 4; ++i) { af[i] = As[aslot[i]]; bf_[i] = Bs[bslot[i]]; }
#pragma unroll
    for (int mi = 0; mi < 4; ++mi)
#pragma unroll
      for (int ni = 0; ni < 4; ++ni)
        acc[mi][ni] = __builtin_amdgcn_mfma_f32_16x16x32_bf16(af[mi], bf_[ni], acc[mi][ni], 0, 0, 0);
    __syncthreads();
  }

#pragma unroll
  for (int mi = 0; mi < 4; ++mi) {
    const int row = bm + wm + mi * 16 + lg * 4;
#pragma unroll
    for (int ni = 0; ni < 4; ++ni) {
      const int col = bn + wn + ni * 16 + lq;
      const float bv = bias ? bias[col] : 0.f;
#pragma unroll
      for (int r = 0; r < 4; ++r) {
        float val = acc[mi][ni][r] + bv;
        if (ACC)  val += C[(size_t)(row + r) * N + col];
        if (RELU) val = fmaxf(val, 0.f);
        if (OBF16) Cb[(size_t)(row + r) * N + col] = f2bf(val);
        else       C [(size_t)(row + r) * N + col] = val;
      }
    }
  }
}

// modes: 0 = f32 out, 1 = f32 out + residual acc, 2 = bf16 out + relu, 3 = bf16 out
static inline void launch_g(const ushort* A, const ushort* BT, const float* bias,
                            float* C, ushort* Cb, int M, int N, int K,
                            int mode, hipStream_t s) {
  dim3 grid(N / 128, M / 128), blk(256);
  if (mode == 0)      gemm_mfma<0, 0, 0><<<grid, blk, 0, s>>>(A, BT, bias, C, Cb, M, N, K);
  else if (mode == 1) gemm_mfma<0, 1, 0><<<grid, blk, 0, s>>>(A, BT, bias, C, Cb, M, N, K);
  else if (mode == 2) gemm_mfma<1, 0, 1><<<grid, blk, 0, s>>>(A, BT, bias, C, Cb, M, N, K);
  else                gemm_mfma<0, 0, 1><<<grid, blk, 0, s>>>(A, BT, bias, C, Cb, M, N, K);
}

// ---------------- MFMA flash attention: one block per (b,h), 4 waves ----------------
// Two-pass (max pass, then exp+PV pass). K staged [208][64] bf16 with XOR slot
// swizzle; V staged transposed [64][256]; P relayout via 1KB/wave LDS scratch.
// All ds_read_b128 patterns <=2-way bank aliasing (free per m136).
template <int CAUSAL>
__global__ __launch_bounds__(256, 2) void attn_mfma_kernel(const ushort* __restrict__ q,
                                                           const ushort* __restrict__ k,
                                                           const ushort* __restrict__ v,
                                                           const int* __restrict__ qids,
                                                           ushort* __restrict__ out) {
  __shared__ short8v Kl[208 * 8];    // 26.6 KB  [kp][slot]  slot = (d/8) ^ (kp&7)
  __shared__ ushort  Vt[64 * 256];   // 32 KB    [d][kp]     16B-slot ^= (d&7)
  __shared__ short8v Pl[1024];       // 16 KB    [wave][i][16 rows][4 slots]
  __shared__ float   padf[224];      // 1 = masked column

  const int bh   = blockIdx.x;
  const int h    = bh & (NH - 1);
  const int b    = bh >> 4;
  const int tid  = threadIdx.x;
  const int w    = tid >> 6;
  const int lane = tid & 63;
  const int lq   = lane & 15;
  const int lg   = lane >> 4;

  // ---- stage K rows 0..207 (zeros beyond 199) ----
  if (tid < 208) {
    const int kp = tid;
    if (kp < SKV) {
      const short8v* src = (const short8v*)(k + ((size_t)(b * SKV + kp)) * DD + h * HDm);
#pragma unroll
      for (int s = 0; s < 8; ++s) Kl[kp * 8 + (s ^ (kp & 7))] = src[s];
    } else {
      const short8v z = {0, 0, 0, 0, 0, 0, 0, 0};
#pragma unroll
      for (int s = 0; s < 8; ++s) Kl[kp * 8 + s] = z;
    }
  }
  // ---- stage V^T cols 0..223 + mask flags ----
  if (tid < 224) {
    const int kp = tid;
    float pf = 1.f;
    if (kp < SKV) {
      pf = CAUSAL ? ((qids[b * SQl + kp] == 0) ? 1.f : 0.f) : 0.f;
      const short8v* src = (const short8v*)(v + ((size_t)(b * SKV + kp)) * DD + h * HDm);
      const int s3 = kp >> 3, k7 = kp & 7;
#pragma unroll
      for (int li = 0; li < 8; ++li) {
        const short8v vv = src[li];
#pragma unroll
        for (int e = 0; e < 8; ++e)
          Vt[(li * 8 + e) * 256 + ((s3 ^ e) * 8) + k7] = (ushort)vv[e];
      }
    } else {
      const int s3 = kp >> 3, k7 = kp & 7;
#pragma unroll
      for (int li = 0; li < 8; ++li)
#pragma unroll
        for (int e = 0; e < 8; ++e)
          Vt[(li * 8 + e) * 256 + ((s3 ^ e) * 8) + k7] = 0;
    }
    padf[kp] = pf;
  }
  __syncthreads();

  // ---- Q fragments: wave w owns m-subtiles {w, w+4, w+8, w+12(<13)} ----
  short8v qf[4][2];
#pragma unroll
  for (int i = 0; i < 4; ++i) {
    const int mt = i * 4 + w;
    if (mt > 12) continue;
    int qrow = mt * 16 + lq;
    if (qrow > SQl - 1) qrow = SQl - 1;
    const ushort* qp = q + ((size_t)(b * SQl + qrow)) * DD + h * HDm + lg * 8;
    qf[i][0] = *(const short8v*)qp;
    qf[i][1] = *(const short8v*)(qp + 32);
  }

  // ---- pass A: row max ----
  float rmax[4][4];
#pragma unroll
  for (int i = 0; i < 4; ++i)
#pragma unroll
    for (int r = 0; r < 4; ++r) rmax[i][r] = -3e38f;

  for (int kt = 0; kt < 13; ++kt) {
    const int kp = kt * 16 + lq;
    const short8v bk0 = Kl[kp * 8 + (lg ^ (kp & 7))];
    const short8v bk1 = Kl[kp * 8 + ((4 + lg) ^ (kp & 7))];
    const float pmask = padf[kp];
#pragma unroll
    for (int i = 0; i < 4; ++i) {
      const int mt = i * 4 + w;
      if (mt > 12) continue;
      floatx4 S = {0.f, 0.f, 0.f, 0.f};
      S = __builtin_amdgcn_mfma_f32_16x16x32_bf16(qf[i][0], bk0, S, 0, 0, 0);
      S = __builtin_amdgcn_mfma_f32_16x16x32_bf16(qf[i][1], bk1, S, 0, 0, 0);
#pragma unroll
      for (int r = 0; r < 4; ++r) {
        const int qrow = mt * 16 + lg * 4 + r;
        bool masked = (pmask != 0.f);
        if (CAUSAL) masked = masked || (kp > qrow);
        const float s = masked ? -3e38f : S[r] * 0.125f;
        rmax[i][r] = fmaxf(rmax[i][r], s);
      }
    }
  }
#pragma unroll
  for (int msk = 1; msk < 16; msk <<= 1)
#pragma unroll
    for (int i = 0; i < 4; ++i)
#pragma unroll
      for (int r = 0; r < 4; ++r)
        rmax[i][r] = fmaxf(rmax[i][r], __shfl_xor(rmax[i][r], msk, 64));

  // ---- pass B: exp, P relayout, PV ----
  float rsum[4][4];
  floatx4 Of[4][4];
  const floatx4 fz = {0.f, 0.f, 0.f, 0.f};
#pragma unroll
  for (int i = 0; i < 4; ++i)
#pragma unroll
    for (int r = 0; r < 4; ++r) { rsum[i][r] = 0.f; Of[i][r] = fz; }

  for (int kc = 0; kc < 7; ++kc) {
#pragma unroll
    for (int t = 0; t < 2; ++t) {
      const int kt = kc * 2 + t;
      const int kp = kt * 16 + lq;
      short8v bk0, bk1;
      float pmask = 1.f;
      if (kt < 13) {
        bk0 = Kl[kp * 8 + (lg ^ (kp & 7))];
        bk1 = Kl[kp * 8 + ((4 + lg) ^ (kp & 7))];
        pmask = padf[kp];
      }
#pragma unroll
      for (int i = 0; i < 4; ++i) {
        const int mt = i * 4 + w;
        if (mt > 12) continue;
        floatx4 S = {0.f, 0.f, 0.f, 0.f};
        if (kt < 13) {
          S = __builtin_amdgcn_mfma_f32_16x16x32_bf16(qf[i][0], bk0, S, 0, 0, 0);
          S = __builtin_amdgcn_mfma_f32_16x16x32_bf16(qf[i][1], bk1, S, 0, 0, 0);
        }
#pragma unroll
        for (int r = 0; r < 4; ++r) {
          const int qrow = mt * 16 + lg * 4 + r;
          bool masked = (kt >= 13) || (pmask != 0.f);
          if (CAUSAL) masked = masked || (kp > qrow);
          const float p = masked ? 0.f : __expf(S[r] * 0.125f - rmax[i][r]);
          rsum[i][r] += p;
          const int qrl  = lg * 4 + r;
          const int kpl  = t * 16 + lq;
          const int slot = (kpl >> 3) ^ ((qrl >> 2) & 3);
          ((ushort*)Pl)[(w * 4 + i) * 512 + qrl * 32 + slot * 8 + (kpl & 7)] = f2bf(p);
        }
      }
    }
    // PV: A = P[qrow][kp-chunk], B = V^T-derived [kp][d]
    short8v vb[4];
#pragma unroll
    for (int dt = 0; dt < 4; ++dt) {
      const int d  = dt * 16 + lq;
      const int sk = kc * 4 + lg;
      vb[dt] = ((const short8v*)Vt)[d * 32 + (sk ^ (d & 7))];
    }
#pragma unroll
    for (int i = 0; i < 4; ++i) {
      const int mt = i * 4 + w;
      if (mt > 12) continue;
      const short8v pa = Pl[(w * 4 + i) * 64 + lq * 4 + (lg ^ ((lq >> 2) & 3))];
#pragma unroll
      for (int dt = 0; dt < 4; ++dt)
        Of[i][dt] = __builtin_amdgcn_mfma_f32_16x16x32_bf16(pa, vb[dt], Of[i][dt], 0, 0, 0);
    }
  }

  // ---- normalize + store ----
#pragma unroll
  for (int msk = 1; msk < 16; msk <<= 1)
#pragma unroll
    for (int i = 0; i < 4; ++i)
#pragma unroll
      for (int r = 0; r < 4; ++r)
        rsum[i][r] += __shfl_xor(rsum[i][r], msk, 64);

#pragma unroll
  for (int i = 0; i < 4; ++i) {
    const int mt = i * 4 + w;
    if (mt > 12) continue;
#pragma unroll
    for (int r = 0; r < 4; ++r) {
      const int qrow = mt * 16 + lg * 4 + r;
      if (qrow >= SQl) continue;
      const float linv = 1.0f / rsum[i][r];
      ushort* op = out + ((size_t)(b * SQl + qrow)) * DD + h * HDm;
#pragma unroll
      for (int dt = 0; dt < 4; ++dt)
        op[dt * 16 + lq] = f2bf(Of[i][dt][r] * linv);
    }
  }
}

// ---------------- driver ----------------
extern "C" void kernel_launch(void* const* d_in, const int* in_sizes, int n_in,
                              void* d_out, int out_size, void* d_ws, size_t ws_size,
                              hipStream_t stream) {
  (void)in_sizes; (void)n_in; (void)out_size; (void)ws_size;

  const int*   qids  = (const int*)  d_in[0];
  const float* key   = (const float*)d_in[1];
  const float* value = (const float*)d_in[2];
  const float* emb   = (const float*)d_in[3];
  const float* ln1_g = (const float*)d_in[4];
  const float* ln2_g = (const float*)d_in[5];
  const float* ln3_g = (const float*)d_in[6];
  const float* ln1_b = (const float*)d_in[7];
  const float* ln2_b = (const float*)d_in[8];
  const float* ln3_b = (const float*)d_in[9];
  const float* Wq_s  = (const float*)d_in[10];
  const float* Wk_s  = (const float*)d_in[11];
  const float* Wv_s  = (const float*)d_in[12];
  const float* Wo_s  = (const float*)d_in[13];
  const float* Wq_c  = (const float*)d_in[14];
  const float* Wk_c  = (const float*)d_in[15];
  const float* Wv_c  = (const float*)d_in[16];
  const float* Wo_c  = (const float*)d_in[17];
  const float* bq_s  = (const float*)d_in[18];
  const float* bk_s  = (const float*)d_in[19];
  const float* bv_s  = (const float*)d_in[20];
  const float* bq_c  = (const float*)d_in[21];
  const float* bk_c  = (const float*)d_in[22];
  const float* bv_c  = (const float*)d_in[23];
  const float* W1    = (const float*)d_in[24];
  const float* bf1   = (const float*)d_in[25];
  const float* W2    = (const float*)d_in[26];
  const float* bf2   = (const float*)d_in[27];
  const float* lnf_g = (const float*)d_in[28];
  const float* lnf_b = (const float*)d_in[29];

  const size_t NTOK = (size_t)BB * SQl * DD;   // 6,553,600
  char* w = (char*)d_ws;
  float*  o   = (float*)w;  w += NTOK * 4;
  ushort* t0b = (ushort*)w; w += NTOK * 2;
  ushort* t1b = (ushort*)w; w += NTOK * 2;
  ushort* t2b = (ushort*)w; w += NTOK * 2;
  ushort* t3b = (ushort*)w; w += NTOK * 2;
  ushort* kb  = (ushort*)w; w += NTOK * 2;
  ushort* vb  = (ushort*)w; w += NTOK * 2;
  ushort* fbb = (ushort*)w; w += (size_t)BB * SQl * FFD * 2;
  ushort* wt  = (ushort*)w; w += (size_t)8 * DD * DD * 2;
  ushort* wt1 = (ushort*)w; w += (size_t)DD * FFD * 2;
  ushort* wt2 = (ushort*)w; w += (size_t)FFD * DD * 2;

  const int M = BB * SQl;                      // 6400

  embed_pe_kernel<<<(int)(NTOK / 256), 256, 0, stream>>>(qids, emb, o);
  cvt_bf16_kernel<<<(int)(NTOK / 8 + 255) / 256, 256, 0, stream>>>(key,   kb, (int)(NTOK / 8));
  cvt_bf16_kernel<<<(int)(NTOK / 8 + 255) / 256, 256, 0, stream>>>(value, vb, (int)(NTOK / 8));

  for (int l = 0; l < NL; ++l) {
    const size_t oDD = (size_t)l * DD * DD;

    P8 p8;
    p8.p[0] = Wq_s + oDD; p8.p[1] = Wk_s + oDD; p8.p[2] = Wv_s + oDD; p8.p[3] = Wo_s + oDD;
    p8.p[4] = Wq_c + oDD; p8.p[5] = Wk_c + oDD; p8.p[6] = Wv_c + oDD; p8.p[7] = Wo_c + oDD;
    transpose_bf16_kernel<<<dim3(DD / 32, DD / 32, 8), 256, 0, stream>>>(p8, wt, DD, DD);
    P8 p1; p1.p[0] = W1 + (size_t)l * DD * FFD;
    transpose_bf16_kernel<<<dim3(FFD / 32, DD / 32, 1), 256, 0, stream>>>(p1, wt1, DD, FFD);
    P8 p2; p2.p[0] = W2 + (size_t)l * FFD * DD;
    transpose_bf16_kernel<<<dim3(DD / 32, FFD / 32, 1), 256, 0, stream>>>(p2, wt2, FFD, DD);

    const size_t WD = (size_t)DD * DD;

    // ---- self-attention ----
    ln_kernel<1><<<M, 256, 0, stream>>>(o, ln1_g + l * DD, ln1_b + l * DD, nullptr, t0b);
    launch_g(t0b, wt + 0 * WD, bq_s + l * DD, nullptr, t1b, M, DD, DD, 3, stream);
    launch_g(t0b, wt + 1 * WD, bk_s + l * DD, nullptr, t2b, M, DD, DD, 3, stream);
    launch_g(t0b, wt + 2 * WD, bv_s + l * DD, nullptr, t3b, M, DD, DD, 3, stream);
    attn_mfma_kernel<1><<<BB * NH, 256, 0, stream>>>(t1b, t2b, t3b, qids, t0b);
    launch_g(t0b, wt + 3 * WD, nullptr, o, nullptr, M, DD, DD, 1, stream);

    // ---- cross-attention ----
    ln_kernel<1><<<M, 256, 0, stream>>>(o, ln2_g + l * DD, ln2_b + l * DD, nullptr, t0b);
    launch_g(t0b, wt + 4 * WD, bq_c + l * DD, nullptr, t1b, M, DD, DD, 3, stream);
    launch_g(kb,  wt + 5 * WD, bk_c + l * DD, nullptr, t2b, M, DD, DD, 3, stream);
    launch_g(vb,  wt + 6 * WD, bv_c + l * DD, nullptr, t3b, M, DD, DD, 3, stream);
    attn_mfma_kernel<0><<<BB * NH, 256, 0, stream>>>(t1b, t2b, t3b, nullptr, t0b);
    launch_g(t0b, wt + 7 * WD, nullptr, o, nullptr, M, DD, DD, 1, stream);

    // ---- feed-forward ----
    ln_kernel<1><<<M, 256, 0, stream>>>(o, ln3_g + l * DD, ln3_b + l * DD, nullptr, t0b);
    launch_g(t0b, wt1, bf1 + l * FFD, nullptr, fbb, M, FFD, DD, 2, stream);
    launch_g(fbb, wt2, bf2 + l * DD,  o, nullptr, M, DD, FFD, 1, stream);
  }

  ln_kernel<0><<<M, 256, 0, stream>>>(o, lnf_g, lnf_b, (float*)d_out, nullptr);
}

// Round 5
// 2711.001 us; speedup vs baseline: 9.6996x; 1.1170x over previous
//
#include <hip/hip_runtime.h>
#include <math.h>

#define BB  32
#define SQl 200
#define SKV 200
#define DD  1024
#define NH  16
#define HDm 64
#define NL  6
#define FFD 2048

typedef __attribute__((ext_vector_type(8))) short  short8v;
typedef __attribute__((ext_vector_type(4))) float  floatx4;

// float -> bf16 bits, round-to-nearest-even
__device__ __forceinline__ ushort f2bf(float x) {
  uint u = __builtin_bit_cast(uint, x);
  u = (u + 0x7FFFu + ((u >> 16) & 1u)) >> 16;
  return (ushort)u;
}

__device__ __forceinline__ void gll16(const void* g, void* l) {
  __builtin_amdgcn_global_load_lds((const __attribute__((address_space(1))) void*)g,
                                   (__attribute__((address_space(3))) void*)l,
                                   16, 0, 0);
}

// ---------------- embedding + sinusoidal positional encoding ----------------
__global__ __launch_bounds__(256) void embed_pe_kernel(const int* __restrict__ qids,
                                                       const float* __restrict__ emb,
                                                       float* __restrict__ x) {
  int idx = blockIdx.x * 256 + threadIdx.x;
  int d   = idx & (DD - 1);
  int row = idx >> 10;
  int s   = row % SQl;
  int tok = qids[row];
  float expo = (float)(d & ~1) * (1.0f / (float)DD);
  float dv   = powf(10000.0f, expo);
  float ang  = (float)s / dv;
  float pe   = (d & 1) ? cosf(ang) : sinf(ang);
  x[idx] = emb[(size_t)tok * DD + d] + pe;
}

// ---------------- f32 -> bf16 elementwise ----------------
__global__ __launch_bounds__(256) void cvt_bf16_kernel(const float* __restrict__ in,
                                                       ushort* __restrict__ out, int n8) {
  int idx = blockIdx.x * 256 + threadIdx.x;
  if (idx >= n8) return;
  const floatx4 va = ((const floatx4*)in)[idx * 2];
  const floatx4 vb = ((const floatx4*)in)[idx * 2 + 1];
  short8v o;
  o[0] = (short)f2bf(va.x); o[1] = (short)f2bf(va.y);
  o[2] = (short)f2bf(va.z); o[3] = (short)f2bf(va.w);
  o[4] = (short)f2bf(vb.x); o[5] = (short)f2bf(vb.y);
  o[6] = (short)f2bf(vb.z); o[7] = (short)f2bf(vb.w);
  ((short8v*)out)[idx] = o;
}

// ---------------- batched transposes: W[K][N] f32 -> WT[N][K] bf16 ----------------
// 48 DxD matrices: z = arr*6 + l. dst layout (1M = 1024*1024 elements):
//   arr 0..2 (Wq_s,Wk_s,Wv_s) -> fused QKV blocks  [l][3M]
//   arr 3 Wo_s -> 18M + l*1M ; arr 4 Wq_c -> 24M + l*1M
//   arr 5 Wk_c -> 30M + l*1M (stacked) ; arr 6 Wv_c -> 36M ; arr 7 Wo_c -> 42M
struct P8 { const float* p[8]; };
__global__ __launch_bounds__(256) void transpose48_kernel(P8 srcs, ushort* __restrict__ dst) {
  __shared__ float t[32][33];
  const size_t MEL = (size_t)DD * DD;
  const int z = blockIdx.z;
  const int arr = z / 6, l = z - arr * 6;
  const size_t base[8] = {0, MEL, 2*MEL, 18*MEL, 24*MEL, 30*MEL, 36*MEL, 42*MEL};
  const size_t lstr[8] = {3*MEL, 3*MEL, 3*MEL, MEL, MEL, MEL, MEL, MEL};
  const float* __restrict__ W = srcs.p[arr] + (size_t)l * MEL;
  ushort* __restrict__ WT = dst + base[arr] + (size_t)l * lstr[arr];
  const int n0 = blockIdx.x * 32, k0 = blockIdx.y * 32;
  const int tx = threadIdx.x & 31, ty = threadIdx.x >> 5;
#pragma unroll
  for (int i = 0; i < 4; ++i)
    t[ty + i * 8][tx] = W[(size_t)(k0 + ty + i * 8) * DD + n0 + tx];
  __syncthreads();
#pragma unroll
  for (int i = 0; i < 4; ++i)
    WT[(size_t)(n0 + ty + i * 8) * DD + k0 + tx] = f2bf(t[tx][ty + i * 8]);
}

// generic per-layer transpose (W1/W2), z = layer
__global__ __launch_bounds__(256) void transposeW_kernel(const float* __restrict__ src,
                                                         ushort* __restrict__ dst,
                                                         int K, int N) {
  __shared__ float t[32][33];
  const int z = blockIdx.z;
  const float* __restrict__ W = src + (size_t)z * K * N;
  ushort* __restrict__ WT = dst + (size_t)z * K * N;
  const int n0 = blockIdx.x * 32, k0 = blockIdx.y * 32;
  const int tx = threadIdx.x & 31, ty = threadIdx.x >> 5;
#pragma unroll
  for (int i = 0; i < 4; ++i)
    t[ty + i * 8][tx] = W[(size_t)(k0 + ty + i * 8) * N + n0 + tx];
  __syncthreads();
#pragma unroll
  for (int i = 0; i < 4; ++i)
    WT[(size_t)(n0 + ty + i * 8) * K + k0 + tx] = f2bf(t[tx][ty + i * 8]);
}

// ---------------- LayerNorm: wave per row, shfl-only reduction ----------------
template <int OBF16>
__global__ __launch_bounds__(256) void ln4_kernel(const float* __restrict__ in,
                                                  const float* __restrict__ gam,
                                                  const float* __restrict__ bet,
                                                  float* __restrict__ outf,
                                                  ushort* __restrict__ outb) {
  const int wid  = threadIdx.x >> 6;
  const int lane = threadIdx.x & 63;
  const int row  = blockIdx.x * 4 + wid;
  const float* ip = in + (size_t)row * DD;

  float4 x[4];
  float s = 0.f, sq = 0.f;
#pragma unroll
  for (int i = 0; i < 4; ++i) {
    x[i] = *(const float4*)&ip[i * 256 + lane * 4];
    s  += x[i].x + x[i].y + x[i].z + x[i].w;
    sq += x[i].x * x[i].x + x[i].y * x[i].y + x[i].z * x[i].z + x[i].w * x[i].w;
  }
#pragma unroll
  for (int msk = 1; msk < 64; msk <<= 1) {
    s  += __shfl_xor(s,  msk, 64);
    sq += __shfl_xor(sq, msk, 64);
  }
  const float m   = s * (1.0f / (float)DD);
  const float var = sq * (1.0f / (float)DD) - m * m;
  const float inv = rsqrtf(var + 1e-9f);

#pragma unroll
  for (int i = 0; i < 4; ++i) {
    const int c = i * 256 + lane * 4;
    const float4 g4 = *(const float4*)&gam[c];
    const float4 b4 = *(const float4*)&bet[c];
    float o0 = (x[i].x - m) * inv * g4.x + b4.x;
    float o1 = (x[i].y - m) * inv * g4.y + b4.y;
    float o2 = (x[i].z - m) * inv * g4.z + b4.z;
    float o3 = (x[i].w - m) * inv * g4.w + b4.w;
    if (OBF16) {
      uint2 pk;
      pk.x = (uint)f2bf(o0) | ((uint)f2bf(o1) << 16);
      pk.y = (uint)f2bf(o2) | ((uint)f2bf(o3) << 16);
      *(uint2*)&outb[(size_t)row * DD + c] = pk;
    } else {
      float4 ov; ov.x = o0; ov.y = o1; ov.z = o2; ov.w = o3;
      *(float4*)&outf[(size_t)row * DD + c] = ov;
    }
  }
}

// ---------------- bf16 MFMA GEMM, BK=64: C[M,N] (+)= A[M,K] @ BT[N,K]^T + bias ----------------
// 128x128 tile, 4 waves (2x2), 64x64/wave. LDS: 1024 16B-slots per operand
// (8 slots/row); physical slot p of row holds k-group p^(row&7) (XOR swizzle,
// staged via pre-swizzled global source + linear global_load_lds dest).
struct BiasP { const float* p[6]; };   // bias.p[col>>10][col&1023]
template <int RELU, int ACC, int OBF16>
__global__ __launch_bounds__(256) void gemm_mfma(const ushort* __restrict__ A,
                                                 const ushort* __restrict__ BT,
                                                 BiasP bias,
                                                 float* __restrict__ C,
                                                 ushort* __restrict__ Cb,
                                                 int M, int N, int K, int ldc) {
  __shared__ short8v As[1024];   // 16 KB
  __shared__ short8v Bs[1024];   // 16 KB
  const int tid  = threadIdx.x;
  const int wid  = tid >> 6;
  const int lane = tid & 63;
  const int bm = blockIdx.y * 128;
  const int bn = blockIdx.x * 128;
  const int wm = (wid >> 1) * 64;
  const int wn = (wid & 1) * 64;
  const int lq = lane & 15;
  const int lg = lane >> 4;

  // staging: thread stages slots {wid*64+lane + 256*i}, i=0..3, per operand
  const int base0 = wid * 64;
  const ushort* aS[4];
  const ushort* bS[4];
#pragma unroll
  for (int i = 0; i < 4; ++i) {
    const int s   = base0 + 256 * i + lane;
    const int row = s >> 3;
    const int kg  = (s & 7) ^ (row & 7);
    aS[i] = A  + (size_t)(bm + row) * K + kg * 8;
    bS[i] = BT + (size_t)(bn + row) * K + kg * 8;
  }

  // fragment read indices (kk=0); kk=1 is index^4
  int aIdx[4], bIdx[4];
#pragma unroll
  for (int i = 0; i < 4; ++i) {
    const int mr = wm + i * 16 + lq;
    aIdx[i] = mr * 8 + (lg ^ (mr & 7));
    const int nr = wn + i * 16 + lq;
    bIdx[i] = nr * 8 + (lg ^ (nr & 7));
  }

  floatx4 acc[4][4];
  const floatx4 fz = {0.f, 0.f, 0.f, 0.f};
#pragma unroll
  for (int mi = 0; mi < 4; ++mi)
#pragma unroll
    for (int ni = 0; ni < 4; ++ni) acc[mi][ni] = fz;

  for (int k0 = 0; k0 < K; k0 += 64) {
#pragma unroll
    for (int i = 0; i < 4; ++i) gll16(aS[i] + k0, &As[base0 + 256 * i]);
#pragma unroll
    for (int i = 0; i < 4; ++i) gll16(bS[i] + k0, &Bs[base0 + 256 * i]);
    __syncthreads();                 // compiler drains vmcnt(0) before barrier
#pragma unroll
    for (int kk = 0; kk < 2; ++kk) {
      short8v af[4], bf_[4];
#pragma unroll
      for (int i = 0; i < 4; ++i) {
        af[i]  = As[aIdx[i] ^ (kk * 4)];
        bf_[i] = Bs[bIdx[i] ^ (kk * 4)];
      }
#pragma unroll
      for (int mi = 0; mi < 4; ++mi)
#pragma unroll
        for (int ni = 0; ni < 4; ++ni)
          acc[mi][ni] = __builtin_amdgcn_mfma_f32_16x16x32_bf16(af[mi], bf_[ni], acc[mi][ni], 0, 0, 0);
    }
    __syncthreads();                 // LDS reads done before next overwrite
  }

  // epilogue: C/D frag col = lane&15, row = (lane>>4)*4 + reg
#pragma unroll
  for (int mi = 0; mi < 4; ++mi) {
    const int row = bm + wm + mi * 16 + lg * 4;
#pragma unroll
    for (int ni = 0; ni < 4; ++ni) {
      const int col = bn + wn + ni * 16 + lq;
      const float* bp = bias.p[col >> 10];
      const float bvv = bp ? bp[col & (DD - 1)] : 0.f;
#pragma unroll
      for (int r = 0; r < 4; ++r) {
        float val = acc[mi][ni][r] + bvv;
        if (ACC)  val += C[(size_t)(row + r) * ldc + col];
        if (RELU) val = fmaxf(val, 0.f);
        if (OBF16) Cb[(size_t)(row + r) * ldc + col] = f2bf(val);
        else       C [(size_t)(row + r) * ldc + col] = val;
      }
    }
  }
}

// modes: 1 = f32 ACC (+bias), 2 = bf16 + relu, 3 = bf16
static inline void launch_g(const ushort* A, const ushort* BT, BiasP bias,
                            float* C, ushort* Cb, int M, int N, int K, int ldc,
                            int mode, hipStream_t s) {
  dim3 grid(N / 128, M / 128), blk(256);
  if (mode == 1)      gemm_mfma<0, 1, 0><<<grid, blk, 0, s>>>(A, BT, bias, C, Cb, M, N, K, ldc);
  else if (mode == 2) gemm_mfma<1, 0, 1><<<grid, blk, 0, s>>>(A, BT, bias, C, Cb, M, N, K, ldc);
  else                gemm_mfma<0, 0, 1><<<grid, blk, 0, s>>>(A, BT, bias, C, Cb, M, N, K, ldc);
}

// ---------------- MFMA flash attention: one block per (b,h), 4 waves ----------------
// (unchanged structure from round 4, with configurable q/k/v row strides)
template <int CAUSAL>
__global__ __launch_bounds__(256, 2) void attn_mfma_kernel(const ushort* __restrict__ q, int qs,
                                                           const ushort* __restrict__ k, int ks,
                                                           const ushort* __restrict__ v, int vs,
                                                           const int* __restrict__ qids,
                                                           ushort* __restrict__ out) {
  __shared__ short8v Kl[208 * 8];
  __shared__ ushort  Vt[64 * 256];
  __shared__ short8v Pl[1024];
  __shared__ float   padf[224];

  const int bh   = blockIdx.x;
  const int h    = bh & (NH - 1);
  const int b    = bh >> 4;
  const int tid  = threadIdx.x;
  const int w    = tid >> 6;
  const int lane = tid & 63;
  const int lq   = lane & 15;
  const int lg   = lane >> 4;

  if (tid < 208) {
    const int kp = tid;
    if (kp < SKV) {
      const short8v* src = (const short8v*)(k + ((size_t)(b * SKV + kp)) * ks + h * HDm);
#pragma unroll
      for (int s = 0; s < 8; ++s) Kl[kp * 8 + (s ^ (kp & 7))] = src[s];
    } else {
      const short8v z = {0, 0, 0, 0, 0, 0, 0, 0};
#pragma unroll
      for (int s = 0; s < 8; ++s) Kl[kp * 8 + s] = z;
    }
  }
  if (tid < 224) {
    const int kp = tid;
    float pf = 1.f;
    if (kp < SKV) {
      pf = CAUSAL ? ((qids[b * SQl + kp] == 0) ? 1.f : 0.f) : 0.f;
      const short8v* src = (const short8v*)(v + ((size_t)(b * SKV + kp)) * vs + h * HDm);
      const int s3 = kp >> 3, k7 = kp & 7;
#pragma unroll
      for (int li = 0; li < 8; ++li) {
        const short8v vv = src[li];
#pragma unroll
        for (int e = 0; e < 8; ++e)
          Vt[(li * 8 + e) * 256 + ((s3 ^ e) * 8) + k7] = (ushort)vv[e];
      }
    } else {
      const int s3 = kp >> 3, k7 = kp & 7;
#pragma unroll
      for (int li = 0; li < 8; ++li)
#pragma unroll
        for (int e = 0; e < 8; ++e)
          Vt[(li * 8 + e) * 256 + ((s3 ^ e) * 8) + k7] = 0;
    }
    padf[kp] = pf;
  }
  __syncthreads();

  short8v qf[4][2];
#pragma unroll
  for (int i = 0; i < 4; ++i) {
    const int mt = i * 4 + w;
    if (mt > 12) continue;
    int qrow = mt * 16 + lq;
    if (qrow > SQl - 1) qrow = SQl - 1;
    const ushort* qp = q + ((size_t)(b * SQl + qrow)) * qs + h * HDm + lg * 8;
    qf[i][0] = *(const short8v*)qp;
    qf[i][1] = *(const short8v*)(qp + 32);
  }

  float rmax[4][4];
#pragma unroll
  for (int i = 0; i < 4; ++i)
#pragma unroll
    for (int r = 0; r < 4; ++r) rmax[i][r] = -3e38f;

  for (int kt = 0; kt < 13; ++kt) {
    const int kp = kt * 16 + lq;
    const short8v bk0 = Kl[kp * 8 + (lg ^ (kp & 7))];
    const short8v bk1 = Kl[kp * 8 + ((4 + lg) ^ (kp & 7))];
    const float pmask = padf[kp];
#pragma unroll
    for (int i = 0; i < 4; ++i) {
      const int mt = i * 4 + w;
      if (mt > 12) continue;
      floatx4 S = {0.f, 0.f, 0.f, 0.f};
      S = __builtin_amdgcn_mfma_f32_16x16x32_bf16(qf[i][0], bk0, S, 0, 0, 0);
      S = __builtin_amdgcn_mfma_f32_16x16x32_bf16(qf[i][1], bk1, S, 0, 0, 0);
#pragma unroll
      for (int r = 0; r < 4; ++r) {
        const int qrow = mt * 16 + lg * 4 + r;
        bool masked = (pmask != 0.f);
        if (CAUSAL) masked = masked || (kp > qrow);
        const float s = masked ? -3e38f : S[r] * 0.125f;
        rmax[i][r] = fmaxf(rmax[i][r], s);
      }
    }
  }
#pragma unroll
  for (int msk = 1; msk < 16; msk <<= 1)
#pragma unroll
    for (int i = 0; i < 4; ++i)
#pragma unroll
      for (int r = 0; r < 4; ++r)
        rmax[i][r] = fmaxf(rmax[i][r], __shfl_xor(rmax[i][r], msk, 64));

  float rsum[4][4];
  floatx4 Of[4][4];
  const floatx4 fz = {0.f, 0.f, 0.f, 0.f};
#pragma unroll
  for (int i = 0; i < 4; ++i)
#pragma unroll
    for (int r = 0; r < 4; ++r) { rsum[i][r] = 0.f; Of[i][r] = fz; }

  for (int kc = 0; kc < 7; ++kc) {
#pragma unroll
    for (int t = 0; t < 2; ++t) {
      const int kt = kc * 2 + t;
      const int kp = kt * 16 + lq;
      short8v bk0, bk1;
      float pmask = 1.f;
      if (kt < 13) {
        bk0 = Kl[kp * 8 + (lg ^ (kp & 7))];
        bk1 = Kl[kp * 8 + ((4 + lg) ^ (kp & 7))];
        pmask = padf[kp];
      }
#pragma unroll
      for (int i = 0; i < 4; ++i) {
        const int mt = i * 4 + w;
        if (mt > 12) continue;
        floatx4 S = {0.f, 0.f, 0.f, 0.f};
        if (kt < 13) {
          S = __builtin_amdgcn_mfma_f32_16x16x32_bf16(qf[i][0], bk0, S, 0, 0, 0);
          S = __builtin_amdgcn_mfma_f32_16x16x32_bf16(qf[i][1], bk1, S, 0, 0, 0);
        }
#pragma unroll
        for (int r = 0; r < 4; ++r) {
          const int qrow = mt * 16 + lg * 4 + r;
          bool masked = (kt >= 13) || (pmask != 0.f);
          if (CAUSAL) masked = masked || (kp > qrow);
          const float p = masked ? 0.f : __expf(S[r] * 0.125f - rmax[i][r]);
          rsum[i][r] += p;
          const int qrl  = lg * 4 + r;
          const int kpl  = t * 16 + lq;
          const int slot = (kpl >> 3) ^ ((qrl >> 2) & 3);
          ((ushort*)Pl)[(w * 4 + i) * 512 + qrl * 32 + slot * 8 + (kpl & 7)] = f2bf(p);
        }
      }
    }
    short8v vb[4];
#pragma unroll
    for (int dt = 0; dt < 4; ++dt) {
      const int d  = dt * 16 + lq;
      const int sk = kc * 4 + lg;
      vb[dt] = ((const short8v*)Vt)[d * 32 + (sk ^ (d & 7))];
    }
#pragma unroll
    for (int i = 0; i < 4; ++i) {
      const int mt = i * 4 + w;
      if (mt > 12) continue;
      const short8v pa = Pl[(w * 4 + i) * 64 + lq * 4 + (lg ^ ((lq >> 2) & 3))];
#pragma unroll
      for (int dt = 0; dt < 4; ++dt)
        Of[i][dt] = __builtin_amdgcn_mfma_f32_16x16x32_bf16(pa, vb[dt], Of[i][dt], 0, 0, 0);
    }
  }

#pragma unroll
  for (int msk = 1; msk < 16; msk <<= 1)
#pragma unroll
    for (int i = 0; i < 4; ++i)
#pragma unroll
      for (int r = 0; r < 4; ++r)
        rsum[i][r] += __shfl_xor(rsum[i][r], msk, 64);

#pragma unroll
  for (int i = 0; i < 4; ++i) {
    const int mt = i * 4 + w;
    if (mt > 12) continue;
#pragma unroll
    for (int r = 0; r < 4; ++r) {
      const int qrow = mt * 16 + lg * 4 + r;
      if (qrow >= SQl) continue;
      const float linv = 1.0f / rsum[i][r];
      ushort* op = out + ((size_t)(b * SQl + qrow)) * DD + h * HDm;
#pragma unroll
      for (int dt = 0; dt < 4; ++dt)
        op[dt * 16 + lq] = f2bf(Of[i][dt][r] * linv);
    }
  }
}

// ---------------- driver ----------------
extern "C" void kernel_launch(void* const* d_in, const int* in_sizes, int n_in,
                              void* d_out, int out_size, void* d_ws, size_t ws_size,
                              hipStream_t stream) {
  (void)in_sizes; (void)n_in; (void)out_size; (void)ws_size;

  const int*   qids  = (const int*)  d_in[0];
  const float* key   = (const float*)d_in[1];
  const float* value = (const float*)d_in[2];
  const float* emb   = (const float*)d_in[3];
  const float* ln1_g = (const float*)d_in[4];
  const float* ln2_g = (const float*)d_in[5];
  const float* ln3_g = (const float*)d_in[6];
  const float* ln1_b = (const float*)d_in[7];
  const float* ln2_b = (const float*)d_in[8];
  const float* ln3_b = (const float*)d_in[9];
  const float* Wq_s  = (const float*)d_in[10];
  const float* Wk_s  = (const float*)d_in[11];
  const float* Wv_s  = (const float*)d_in[12];
  const float* Wo_s  = (const float*)d_in[13];
  const float* Wq_c  = (const float*)d_in[14];
  const float* Wk_c  = (const float*)d_in[15];
  const float* Wv_c  = (const float*)d_in[16];
  const float* Wo_c  = (const float*)d_in[17];
  const float* bq_s  = (const float*)d_in[18];
  const float* bk_s  = (const float*)d_in[19];
  const float* bv_s  = (const float*)d_in[20];
  const float* bq_c  = (const float*)d_in[21];
  const float* bk_c  = (const float*)d_in[22];
  const float* bv_c  = (const float*)d_in[23];
  const float* W1    = (const float*)d_in[24];
  const float* bf1   = (const float*)d_in[25];
  const float* W2    = (const float*)d_in[26];
  const float* bf2   = (const float*)d_in[27];
  const float* lnf_g = (const float*)d_in[28];
  const float* lnf_b = (const float*)d_in[29];

  const size_t NTOK = (size_t)BB * SQl * DD;     // 6,553,600
  const size_t MEL  = (size_t)DD * DD;
  char* w = (char*)d_ws;
  float*  o    = (float*)w;  w += NTOK * 4;
  ushort* t0b  = (ushort*)w; w += NTOK * 2;
  ushort* qkv  = (ushort*)w; w += (size_t)BB * SQl * 3 * DD * 2;
  ushort* kc   = (ushort*)w; w += (size_t)BB * SQl * 6 * DD * 2;
  ushort* vc   = (ushort*)w; w += (size_t)BB * SQl * 6 * DD * 2;
  ushort* kb   = (ushort*)w; w += NTOK * 2;
  ushort* vb   = (ushort*)w; w += NTOK * 2;
  ushort* fbb  = (ushort*)w; w += (size_t)BB * SQl * FFD * 2;
  ushort* wt   = (ushort*)w; w += 48 * MEL * 2;
  ushort* wt1  = (ushort*)w; w += (size_t)NL * DD * FFD * 2;
  ushort* wt2  = (ushort*)w; w += (size_t)NL * FFD * DD * 2;

  const int M = BB * SQl;                        // 6400
  const BiasP nob = {{nullptr, nullptr, nullptr, nullptr, nullptr, nullptr}};

  embed_pe_kernel<<<(int)(NTOK / 256), 256, 0, stream>>>(qids, emb, o);
  cvt_bf16_kernel<<<(int)(NTOK / 8 + 255) / 256, 256, 0, stream>>>(key,   kb, (int)(NTOK / 8));
  cvt_bf16_kernel<<<(int)(NTOK / 8 + 255) / 256, 256, 0, stream>>>(value, vb, (int)(NTOK / 8));

  // all weight transposes up front (3 launches)
  P8 p8 = {{Wq_s, Wk_s, Wv_s, Wo_s, Wq_c, Wk_c, Wv_c, Wo_c}};
  transpose48_kernel<<<dim3(32, 32, 48), 256, 0, stream>>>(p8, wt);
  transposeW_kernel<<<dim3(FFD / 32, DD / 32, NL), 256, 0, stream>>>(W1, wt1, DD, FFD);
  transposeW_kernel<<<dim3(DD / 32, FFD / 32, NL), 256, 0, stream>>>(W2, wt2, FFD, DD);

  ushort* wtQKV = wt;                 // [l][3M]
  ushort* wtOs  = wt + 18 * MEL;      // [l][1M]
  ushort* wtQc  = wt + 24 * MEL;
  ushort* wtKc  = wt + 30 * MEL;      // stacked 6 layers
  ushort* wtVc  = wt + 36 * MEL;
  ushort* wtOc  = wt + 42 * MEL;

  // cross-attention K/V for ALL layers (layer-invariant A): two N=6144 GEMMs
  {
    BiasP bk6, bv6;
#pragma unroll
    for (int l = 0; l < NL; ++l) { bk6.p[l] = bk_c + l * DD; bv6.p[l] = bv_c + l * DD; }
    launch_g(kb, wtKc, bk6, nullptr, kc, M, 6 * DD, DD, 6 * DD, 3, stream);
    launch_g(vb, wtVc, bv6, nullptr, vc, M, 6 * DD, DD, 6 * DD, 3, stream);
  }

  for (int l = 0; l < NL; ++l) {
    // ---- self-attention ----
    ln4_kernel<1><<<M / 4, 256, 0, stream>>>(o, ln1_g + l * DD, ln1_b + l * DD, nullptr, t0b);
    BiasP bqkv = {{bq_s + l * DD, bk_s + l * DD, bv_s + l * DD, nullptr, nullptr, nullptr}};
    launch_g(t0b, wtQKV + l * 3 * MEL, bqkv, nullptr, qkv, M, 3 * DD, DD, 3 * DD, 3, stream);
    attn_mfma_kernel<1><<<BB * NH, 256, 0, stream>>>(qkv, 3 * DD, qkv + DD, 3 * DD,
                                                     qkv + 2 * DD, 3 * DD, qids, t0b);
    launch_g(t0b, wtOs + l * MEL, nob, o, nullptr, M, DD, DD, DD, 1, stream);

    // ---- cross-attention ----
    ln4_kernel<1><<<M / 4, 256, 0, stream>>>(o, ln2_g + l * DD, ln2_b + l * DD, nullptr, t0b);
    BiasP bqc = {{bq_c + l * DD, nullptr, nullptr, nullptr, nullptr, nullptr}};
    launch_g(t0b, wtQc + l * MEL, bqc, nullptr, qkv, M, DD, DD, 3 * DD, 3, stream);
    attn_mfma_kernel<0><<<BB * NH, 256, 0, stream>>>(qkv, 3 * DD, kc + l * DD, 6 * DD,
                                                     vc + l * DD, 6 * DD, nullptr, t0b);
    launch_g(t0b, wtOc + l * MEL, nob, o, nullptr, M, DD, DD, DD, 1, stream);

    // ---- feed-forward ----
    ln4_kernel<1><<<M / 4, 256, 0, stream>>>(o, ln3_g + l * DD, ln3_b + l * DD, nullptr, t0b);
    BiasP bf1p = {{bf1 + l * FFD, bf1 + l * FFD + DD, nullptr, nullptr, nullptr, nullptr}};
    launch_g(t0b, wt1 + (size_t)l * DD * FFD, bf1p, nullptr, fbb, M, FFD, DD, FFD, 2, stream);
    BiasP bf2p = {{bf2 + l * DD, nullptr, nullptr, nullptr, nullptr, nullptr}};
    launch_g(fbb, wt2 + (size_t)l * FFD * DD, bf2p, o, nullptr, M, DD, FFD, DD, 1, stream);
  }

  ln4_kernel<0><<<M / 4, 256, 0, stream>>>(o, lnf_g, lnf_b, (float*)d_out, nullptr);
}

// Round 6
// 2633.044 us; speedup vs baseline: 9.9868x; 1.0296x over previous
//
#include <hip/hip_runtime.h>
#include <math.h>

#define BB  32
#define SQl 200
#define SKV 200
#define DD  1024
#define NH  16
#define HDm 64
#define NL  6
#define FFD 2048

typedef __attribute__((ext_vector_type(8))) short  short8v;
typedef __attribute__((ext_vector_type(4))) float  floatx4;

#define SBAR()  asm volatile("s_barrier" ::: "memory")
#define VMCNT6() asm volatile("s_waitcnt vmcnt(6)" ::: "memory")
#define VMCNT0() asm volatile("s_waitcnt vmcnt(0)" ::: "memory")

// float -> bf16 bits, round-to-nearest-even
__device__ __forceinline__ ushort f2bf(float x) {
  uint u = __builtin_bit_cast(uint, x);
  u = (u + 0x7FFFu + ((u >> 16) & 1u)) >> 16;
  return (ushort)u;
}

__device__ __forceinline__ void gll16(const void* g, void* l) {
  __builtin_amdgcn_global_load_lds((const __attribute__((address_space(1))) void*)g,
                                   (__attribute__((address_space(3))) void*)l,
                                   16, 0, 0);
}

// ---------------- embedding + sinusoidal positional encoding ----------------
__global__ __launch_bounds__(256) void embed_pe_kernel(const int* __restrict__ qids,
                                                       const float* __restrict__ emb,
                                                       float* __restrict__ x) {
  int idx = blockIdx.x * 256 + threadIdx.x;
  int d   = idx & (DD - 1);
  int row = idx >> 10;
  int s   = row % SQl;
  int tok = qids[row];
  float expo = (float)(d & ~1) * (1.0f / (float)DD);
  float dv   = powf(10000.0f, expo);
  float ang  = (float)s / dv;
  float pe   = (d & 1) ? cosf(ang) : sinf(ang);
  x[idx] = emb[(size_t)tok * DD + d] + pe;
}

// ---------------- f32 -> bf16 elementwise ----------------
__global__ __launch_bounds__(256) void cvt_bf16_kernel(const float* __restrict__ in,
                                                       ushort* __restrict__ out, int n8) {
  int idx = blockIdx.x * 256 + threadIdx.x;
  if (idx >= n8) return;
  const floatx4 va = ((const floatx4*)in)[idx * 2];
  const floatx4 vb = ((const floatx4*)in)[idx * 2 + 1];
  short8v o;
  o[0] = (short)f2bf(va.x); o[1] = (short)f2bf(va.y);
  o[2] = (short)f2bf(va.z); o[3] = (short)f2bf(va.w);
  o[4] = (short)f2bf(vb.x); o[5] = (short)f2bf(vb.y);
  o[6] = (short)f2bf(vb.z); o[7] = (short)f2bf(vb.w);
  ((short8v*)out)[idx] = o;
}

// ---------------- batched transposes: W[K][N] f32 -> WT[N][K] bf16 ----------------
struct P8 { const float* p[8]; };
__global__ __launch_bounds__(256) void transpose48_kernel(P8 srcs, ushort* __restrict__ dst) {
  __shared__ float t[32][33];
  const size_t MEL = (size_t)DD * DD;
  const int z = blockIdx.z;
  const int arr = z / 6, l = z - arr * 6;
  const size_t base[8] = {0, MEL, 2*MEL, 18*MEL, 24*MEL, 30*MEL, 36*MEL, 42*MEL};
  const size_t lstr[8] = {3*MEL, 3*MEL, 3*MEL, MEL, MEL, MEL, MEL, MEL};
  const float* __restrict__ W = srcs.p[arr] + (size_t)l * MEL;
  ushort* __restrict__ WT = dst + base[arr] + (size_t)l * lstr[arr];
  const int n0 = blockIdx.x * 32, k0 = blockIdx.y * 32;
  const int tx = threadIdx.x & 31, ty = threadIdx.x >> 5;
#pragma unroll
  for (int i = 0; i < 4; ++i)
    t[ty + i * 8][tx] = W[(size_t)(k0 + ty + i * 8) * DD + n0 + tx];
  __syncthreads();
#pragma unroll
  for (int i = 0; i < 4; ++i)
    WT[(size_t)(n0 + ty + i * 8) * DD + k0 + tx] = f2bf(t[tx][ty + i * 8]);
}

__global__ __launch_bounds__(256) void transposeW_kernel(const float* __restrict__ src,
                                                         ushort* __restrict__ dst,
                                                         int K, int N) {
  __shared__ float t[32][33];
  const int z = blockIdx.z;
  const float* __restrict__ W = src + (size_t)z * K * N;
  ushort* __restrict__ WT = dst + (size_t)z * K * N;
  const int n0 = blockIdx.x * 32, k0 = blockIdx.y * 32;
  const int tx = threadIdx.x & 31, ty = threadIdx.x >> 5;
#pragma unroll
  for (int i = 0; i < 4; ++i)
    t[ty + i * 8][tx] = W[(size_t)(k0 + ty + i * 8) * N + n0 + tx];
  __syncthreads();
#pragma unroll
  for (int i = 0; i < 4; ++i)
    WT[(size_t)(n0 + ty + i * 8) * K + k0 + tx] = f2bf(t[tx][ty + i * 8]);
}

// ---------------- LayerNorm: wave per row, shfl-only reduction ----------------
template <int OBF16>
__global__ __launch_bounds__(256) void ln4_kernel(const float* __restrict__ in,
                                                  const float* __restrict__ gam,
                                                  const float* __restrict__ bet,
                                                  float* __restrict__ outf,
                                                  ushort* __restrict__ outb) {
  const int wid  = threadIdx.x >> 6;
  const int lane = threadIdx.x & 63;
  const int row  = blockIdx.x * 4 + wid;
  const float* ip = in + (size_t)row * DD;

  float4 x[4];
  float s = 0.f, sq = 0.f;
#pragma unroll
  for (int i = 0; i < 4; ++i) {
    x[i] = *(const float4*)&ip[i * 256 + lane * 4];
    s  += x[i].x + x[i].y + x[i].z + x[i].w;
    sq += x[i].x * x[i].x + x[i].y * x[i].y + x[i].z * x[i].z + x[i].w * x[i].w;
  }
#pragma unroll
  for (int msk = 1; msk < 64; msk <<= 1) {
    s  += __shfl_xor(s,  msk, 64);
    sq += __shfl_xor(sq, msk, 64);
  }
  const float m   = s * (1.0f / (float)DD);
  const float var = sq * (1.0f / (float)DD) - m * m;
  const float inv = rsqrtf(var + 1e-9f);

#pragma unroll
  for (int i = 0; i < 4; ++i) {
    const int c = i * 256 + lane * 4;
    const float4 g4 = *(const float4*)&gam[c];
    const float4 b4 = *(const float4*)&bet[c];
    float o0 = (x[i].x - m) * inv * g4.x + b4.x;
    float o1 = (x[i].y - m) * inv * g4.y + b4.y;
    float o2 = (x[i].z - m) * inv * g4.z + b4.z;
    float o3 = (x[i].w - m) * inv * g4.w + b4.w;
    if (OBF16) {
      uint2 pk;
      pk.x = (uint)f2bf(o0) | ((uint)f2bf(o1) << 16);
      pk.y = (uint)f2bf(o2) | ((uint)f2bf(o3) << 16);
      *(uint2*)&outb[(size_t)row * DD + c] = pk;
    } else {
      float4 ov; ov.x = o0; ov.y = o1; ov.z = o2; ov.w = o3;
      *(float4*)&outf[(size_t)row * DD + c] = ov;
    }
  }
}

// ---------------- bf16 MFMA GEMM, 256x128 tile, BK=64, 8 waves, 3-deep pipeline ----
// Triple-buffered LDS (144 KB). Per K-tile: 2 phases, each {8 ds_read_b128 frags,
// issue 3 global_load_lds for tile t+2, s_barrier, setprio(1), 16 MFMA, setprio(0),
// s_barrier}; tile ends with counted s_waitcnt vmcnt(6) (never 0 in-loop) so the
// next tile's loads stay in flight across the barrier (T3+T4+T5).
// LDS layout per buffer: row-major [rows][8 slots of 16B]; physical slot p of row
// holds k-group p^(row&7) (XOR swizzle; linear gll_lds dest + pre-swizzled source).
struct BiasP { const float* p[6]; };   // bias.p[col>>10][col&1023]
template <int RELU, int ACC, int OBF16>
__global__ __launch_bounds__(512) void gemm8_mfma(const ushort* __restrict__ A,
                                                  const ushort* __restrict__ BT,
                                                  BiasP bias,
                                                  float* __restrict__ C,
                                                  ushort* __restrict__ Cb,
                                                  int M, int N, int K, int ldc) {
  __shared__ short8v As[3 * 2048];   // 96 KB : 3 x [256 rows][8 slots]
  __shared__ short8v Bs[3 * 1024];   // 48 KB : 3 x [128 rows][8 slots]
  const int tid  = threadIdx.x;
  const int w    = tid >> 6;          // 0..7
  const int lane = tid & 63;
  const int bm = blockIdx.y * 256;
  const int bn = blockIdx.x * 128;
  const int wm = (w >> 1) * 64;       // 4 M-waves
  const int wn = (w & 1) * 64;        // 2 N-waves
  const int lq = lane & 15;
  const int lg = lane >> 4;

  // staging sources (pre-swizzled global addresses); wave-uniform LDS dests
  const ushort* aS[4];
  const ushort* bS[2];
#pragma unroll
  for (int i = 0; i < 4; ++i) {
    const int s   = w * 64 + i * 512 + lane;   // A slot in [0,2048)
    const int row = s >> 3;
    const int kg  = (s & 7) ^ (row & 7);
    aS[i] = A + (size_t)(bm + row) * K + kg * 8;
  }
#pragma unroll
  for (int i = 0; i < 2; ++i) {
    const int s   = w * 64 + i * 512 + lane;   // B slot in [0,1024)
    const int row = s >> 3;
    const int kg  = (s & 7) ^ (row & 7);
    bS[i] = BT + (size_t)(bn + row) * K + kg * 8;
  }

  // fragment read indices for ksub0; ksub1 = idx^4
  int aIdx[4], bIdx[4];
#pragma unroll
  for (int i = 0; i < 4; ++i) {
    const int mr = wm + i * 16 + lq;
    aIdx[i] = mr * 8 + (lg ^ (mr & 7));
    const int nr = wn + i * 16 + lq;
    bIdx[i] = nr * 8 + (lg ^ (nr & 7));
  }

  floatx4 acc[4][4];
  const floatx4 fz = {0.f, 0.f, 0.f, 0.f};
#pragma unroll
  for (int mi = 0; mi < 4; ++mi)
#pragma unroll
    for (int ni = 0; ni < 4; ++ni) acc[mi][ni] = fz;

  const int nt = K >> 6;

  // prologue: stage tiles 0 and 1; wait tile 0 only (6 of 12 remain outstanding)
#pragma unroll
  for (int b = 0; b < 2; ++b) {
    const int koff = b * 64;
    gll16(aS[0] + koff, &As[b * 2048 + w * 64 + 0 * 512]);
    gll16(aS[1] + koff, &As[b * 2048 + w * 64 + 1 * 512]);
    gll16(aS[2] + koff, &As[b * 2048 + w * 64 + 2 * 512]);
    gll16(aS[3] + koff, &As[b * 2048 + w * 64 + 3 * 512]);
    gll16(bS[0] + koff, &Bs[b * 1024 + w * 64 + 0 * 512]);
    gll16(bS[1] + koff, &Bs[b * 1024 + w * 64 + 1 * 512]);
  }
  VMCNT6();
  SBAR();

  int cur = 0;
  for (int t = 0; t < nt; ++t) {
    int b2 = cur + 2; if (b2 >= 3) b2 -= 3;         // buffer for tile t+2
    const int koff2 = (t + 2) * 64;
    const bool pf = (t + 2) < nt;
    const int cbA = cur * 2048, cbB = cur * 1024;
    short8v* dA = &As[b2 * 2048 + w * 64];
    short8v* dB = &Bs[b2 * 1024 + w * 64];

    // ---- phase 1: ksub0 ----
    short8v af[4], bf_[4];
#pragma unroll
    for (int i = 0; i < 4; ++i) { af[i] = As[cbA + aIdx[i]]; bf_[i] = Bs[cbB + bIdx[i]]; }
    if (pf) {
      gll16(aS[0] + koff2, dA + 0 * 512);
      gll16(aS[1] + koff2, dA + 1 * 512);
      gll16(bS[0] + koff2, dB + 0 * 512);
    }
    SBAR();
    __builtin_amdgcn_s_setprio(1);
#pragma unroll
    for (int mi = 0; mi < 4; ++mi)
#pragma unroll
      for (int ni = 0; ni < 4; ++ni)
        acc[mi][ni] = __builtin_amdgcn_mfma_f32_16x16x32_bf16(af[mi], bf_[ni], acc[mi][ni], 0, 0, 0);
    __builtin_amdgcn_s_setprio(0);
    SBAR();

    // ---- phase 2: ksub1 ----
#pragma unroll
    for (int i = 0; i < 4; ++i) { af[i] = As[cbA + (aIdx[i] ^ 4)]; bf_[i] = Bs[cbB + (bIdx[i] ^ 4)]; }
    if (pf) {
      gll16(aS[2] + koff2, dA + 2 * 512);
      gll16(aS[3] + koff2, dA + 3 * 512);
      gll16(bS[1] + koff2, dB + 1 * 512);
    }
    SBAR();
    __builtin_amdgcn_s_setprio(1);
#pragma unroll
    for (int mi = 0; mi < 4; ++mi)
#pragma unroll
      for (int ni = 0; ni < 4; ++ni)
        acc[mi][ni] = __builtin_amdgcn_mfma_f32_16x16x32_bf16(af[mi], bf_[ni], acc[mi][ni], 0, 0, 0);
    __builtin_amdgcn_s_setprio(0);

    // ---- tile end: counted wait (t+1's loads done; t+2's stay in flight) ----
    if (pf) { VMCNT6(); } else { VMCNT0(); }
    SBAR();
    cur = cur + 1; if (cur >= 3) cur -= 3;
  }

  // epilogue: C/D frag col = lane&15, row = (lane>>4)*4 + reg
#pragma unroll
  for (int mi = 0; mi < 4; ++mi) {
    const int row = bm + wm + mi * 16 + lg * 4;
#pragma unroll
    for (int ni = 0; ni < 4; ++ni) {
      const int col = bn + wn + ni * 16 + lq;
      const float* bp = bias.p[col >> 10];
      const float bvv = bp ? bp[col & (DD - 1)] : 0.f;
#pragma unroll
      for (int r = 0; r < 4; ++r) {
        float val = acc[mi][ni][r] + bvv;
        if (ACC)  val += C[(size_t)(row + r) * ldc + col];
        if (RELU) val = fmaxf(val, 0.f);
        if (OBF16) Cb[(size_t)(row + r) * ldc + col] = f2bf(val);
        else       C [(size_t)(row + r) * ldc + col] = val;
      }
    }
  }
}

// modes: 1 = f32 ACC (+bias), 2 = bf16 + relu, 3 = bf16
static inline void launch_g(const ushort* A, const ushort* BT, BiasP bias,
                            float* C, ushort* Cb, int M, int N, int K, int ldc,
                            int mode, hipStream_t s) {
  dim3 grid(N / 128, M / 256), blk(512);
  if (mode == 1)      gemm8_mfma<0, 1, 0><<<grid, blk, 0, s>>>(A, BT, bias, C, Cb, M, N, K, ldc);
  else if (mode == 2) gemm8_mfma<1, 0, 1><<<grid, blk, 0, s>>>(A, BT, bias, C, Cb, M, N, K, ldc);
  else                gemm8_mfma<0, 0, 1><<<grid, blk, 0, s>>>(A, BT, bias, C, Cb, M, N, K, ldc);
}

// ---------------- MFMA flash attention: one block per (b,h), 4 waves ----------------
template <int CAUSAL>
__global__ __launch_bounds__(256, 2) void attn_mfma_kernel(const ushort* __restrict__ q, int qs,
                                                           const ushort* __restrict__ k, int ks,
                                                           const ushort* __restrict__ v, int vs,
                                                           const int* __restrict__ qids,
                                                           ushort* __restrict__ out) {
  __shared__ short8v Kl[208 * 8];
  __shared__ ushort  Vt[64 * 256];
  __shared__ short8v Pl[1024];
  __shared__ float   padf[224];

  const int bh   = blockIdx.x;
  const int h    = bh & (NH - 1);
  const int b    = bh >> 4;
  const int tid  = threadIdx.x;
  const int w    = tid >> 6;
  const int lane = tid & 63;
  const int lq   = lane & 15;
  const int lg   = lane >> 4;

  if (tid < 208) {
    const int kp = tid;
    if (kp < SKV) {
      const short8v* src = (const short8v*)(k + ((size_t)(b * SKV + kp)) * ks + h * HDm);
#pragma unroll
      for (int s = 0; s < 8; ++s) Kl[kp * 8 + (s ^ (kp & 7))] = src[s];
    } else {
      const short8v z = {0, 0, 0, 0, 0, 0, 0, 0};
#pragma unroll
      for (int s = 0; s < 8; ++s) Kl[kp * 8 + s] = z;
    }
  }
  if (tid < 224) {
    const int kp = tid;
    float pf = 1.f;
    if (kp < SKV) {
      pf = CAUSAL ? ((qids[b * SQl + kp] == 0) ? 1.f : 0.f) : 0.f;
      const short8v* src = (const short8v*)(v + ((size_t)(b * SKV + kp)) * vs + h * HDm);
      const int s3 = kp >> 3, k7 = kp & 7;
#pragma unroll
      for (int li = 0; li < 8; ++li) {
        const short8v vv = src[li];
#pragma unroll
        for (int e = 0; e < 8; ++e)
          Vt[(li * 8 + e) * 256 + ((s3 ^ e) * 8) + k7] = (ushort)vv[e];
      }
    } else {
      const int s3 = kp >> 3, k7 = kp & 7;
#pragma unroll
      for (int li = 0; li < 8; ++li)
#pragma unroll
        for (int e = 0; e < 8; ++e)
          Vt[(li * 8 + e) * 256 + ((s3 ^ e) * 8) + k7] = 0;
    }
    padf[kp] = pf;
  }
  __syncthreads();

  short8v qf[4][2];
#pragma unroll
  for (int i = 0; i < 4; ++i) {
    const int mt = i * 4 + w;
    if (mt > 12) continue;
    int qrow = mt * 16 + lq;
    if (qrow > SQl - 1) qrow = SQl - 1;
    const ushort* qp = q + ((size_t)(b * SQl + qrow)) * qs + h * HDm + lg * 8;
    qf[i][0] = *(const short8v*)qp;
    qf[i][1] = *(const short8v*)(qp + 32);
  }

  float rmax[4][4];
#pragma unroll
  for (int i = 0; i < 4; ++i)
#pragma unroll
    for (int r = 0; r < 4; ++r) rmax[i][r] = -3e38f;

  for (int kt = 0; kt < 13; ++kt) {
    const int kp = kt * 16 + lq;
    const short8v bk0 = Kl[kp * 8 + (lg ^ (kp & 7))];
    const short8v bk1 = Kl[kp * 8 + ((4 + lg) ^ (kp & 7))];
    const float pmask = padf[kp];
#pragma unroll
    for (int i = 0; i < 4; ++i) {
      const int mt = i * 4 + w;
      if (mt > 12) continue;
      floatx4 S = {0.f, 0.f, 0.f, 0.f};
      S = __builtin_amdgcn_mfma_f32_16x16x32_bf16(qf[i][0], bk0, S, 0, 0, 0);
      S = __builtin_amdgcn_mfma_f32_16x16x32_bf16(qf[i][1], bk1, S, 0, 0, 0);
#pragma unroll
      for (int r = 0; r < 4; ++r) {
        const int qrow = mt * 16 + lg * 4 + r;
        bool masked = (pmask != 0.f);
        if (CAUSAL) masked = masked || (kp > qrow);
        const float s = masked ? -3e38f : S[r] * 0.125f;
        rmax[i][r] = fmaxf(rmax[i][r], s);
      }
    }
  }
#pragma unroll
  for (int msk = 1; msk < 16; msk <<= 1)
#pragma unroll
    for (int i = 0; i < 4; ++i)
#pragma unroll
      for (int r = 0; r < 4; ++r)
        rmax[i][r] = fmaxf(rmax[i][r], __shfl_xor(rmax[i][r], msk, 64));

  float rsum[4][4];
  floatx4 Of[4][4];
  const floatx4 fz = {0.f, 0.f, 0.f, 0.f};
#pragma unroll
  for (int i = 0; i < 4; ++i)
#pragma unroll
    for (int r = 0; r < 4; ++r) { rsum[i][r] = 0.f; Of[i][r] = fz; }

  for (int kc = 0; kc < 7; ++kc) {
#pragma unroll
    for (int t = 0; t < 2; ++t) {
      const int kt = kc * 2 + t;
      const int kp = kt * 16 + lq;
      short8v bk0, bk1;
      float pmask = 1.f;
      if (kt < 13) {
        bk0 = Kl[kp * 8 + (lg ^ (kp & 7))];
        bk1 = Kl[kp * 8 + ((4 + lg) ^ (kp & 7))];
        pmask = padf[kp];
      }
#pragma unroll
      for (int i = 0; i < 4; ++i) {
        const int mt = i * 4 + w;
        if (mt > 12) continue;
        floatx4 S = {0.f, 0.f, 0.f, 0.f};
        if (kt < 13) {
          S = __builtin_amdgcn_mfma_f32_16x16x32_bf16(qf[i][0], bk0, S, 0, 0, 0);
          S = __builtin_amdgcn_mfma_f32_16x16x32_bf16(qf[i][1], bk1, S, 0, 0, 0);
        }
#pragma unroll
        for (int r = 0; r < 4; ++r) {
          const int qrow = mt * 16 + lg * 4 + r;
          bool masked = (kt >= 13) || (pmask != 0.f);
          if (CAUSAL) masked = masked || (kp > qrow);
          const float p = masked ? 0.f : __expf(S[r] * 0.125f - rmax[i][r]);
          rsum[i][r] += p;
          const int qrl  = lg * 4 + r;
          const int kpl  = t * 16 + lq;
          const int slot = (kpl >> 3) ^ ((qrl >> 2) & 3);
          ((ushort*)Pl)[(w * 4 + i) * 512 + qrl * 32 + slot * 8 + (kpl & 7)] = f2bf(p);
        }
      }
    }
    short8v vb[4];
#pragma unroll
    for (int dt = 0; dt < 4; ++dt) {
      const int d  = dt * 16 + lq;
      const int sk = kc * 4 + lg;
      vb[dt] = ((const short8v*)Vt)[d * 32 + (sk ^ (d & 7))];
    }
#pragma unroll
    for (int i = 0; i < 4; ++i) {
      const int mt = i * 4 + w;
      if (mt > 12) continue;
      const short8v pa = Pl[(w * 4 + i) * 64 + lq * 4 + (lg ^ ((lq >> 2) & 3))];
#pragma unroll
      for (int dt = 0; dt < 4; ++dt)
        Of[i][dt] = __builtin_amdgcn_mfma_f32_16x16x32_bf16(pa, vb[dt], Of[i][dt], 0, 0, 0);
    }
  }

#pragma unroll
  for (int msk = 1; msk < 16; msk <<= 1)
#pragma unroll
    for (int i = 0; i < 4; ++i)
#pragma unroll
      for (int r = 0; r < 4; ++r)
        rsum[i][r] += __shfl_xor(rsum[i][r], msk, 64);

#pragma unroll
  for (int i = 0; i < 4; ++i) {
    const int mt = i * 4 + w;
    if (mt > 12) continue;
#pragma unroll
    for (int r = 0; r < 4; ++r) {
      const int qrow = mt * 16 + lg * 4 + r;
      if (qrow >= SQl) continue;
      const float linv = 1.0f / rsum[i][r];
      ushort* op = out + ((size_t)(b * SQl + qrow)) * DD + h * HDm;
#pragma unroll
      for (int dt = 0; dt < 4; ++dt)
        op[dt * 16 + lq] = f2bf(Of[i][dt][r] * linv);
    }
  }
}

// ---------------- driver ----------------
extern "C" void kernel_launch(void* const* d_in, const int* in_sizes, int n_in,
                              void* d_out, int out_size, void* d_ws, size_t ws_size,
                              hipStream_t stream) {
  (void)in_sizes; (void)n_in; (void)out_size; (void)ws_size;

  const int*   qids  = (const int*)  d_in[0];
  const float* key   = (const float*)d_in[1];
  const float* value = (const float*)d_in[2];
  const float* emb   = (const float*)d_in[3];
  const float* ln1_g = (const float*)d_in[4];
  const float* ln2_g = (const float*)d_in[5];
  const float* ln3_g = (const float*)d_in[6];
  const float* ln1_b = (const float*)d_in[7];
  const float* ln2_b = (const float*)d_in[8];
  const float* ln3_b = (const float*)d_in[9];
  const float* Wq_s  = (const float*)d_in[10];
  const float* Wk_s  = (const float*)d_in[11];
  const float* Wv_s  = (const float*)d_in[12];
  const float* Wo_s  = (const float*)d_in[13];
  const float* Wq_c  = (const float*)d_in[14];
  const float* Wk_c  = (const float*)d_in[15];
  const float* Wv_c  = (const float*)d_in[16];
  const float* Wo_c  = (const float*)d_in[17];
  const float* bq_s  = (const float*)d_in[18];
  const float* bk_s  = (const float*)d_in[19];
  const float* bv_s  = (const float*)d_in[20];
  const float* bq_c  = (const float*)d_in[21];
  const float* bk_c  = (const float*)d_in[22];
  const float* bv_c  = (const float*)d_in[23];
  const float* W1    = (const float*)d_in[24];
  const float* bf1   = (const float*)d_in[25];
  const float* W2    = (const float*)d_in[26];
  const float* bf2   = (const float*)d_in[27];
  const float* lnf_g = (const float*)d_in[28];
  const float* lnf_b = (const float*)d_in[29];

  const size_t NTOK = (size_t)BB * SQl * DD;     // 6,553,600
  const size_t MEL  = (size_t)DD * DD;
  char* w = (char*)d_ws;
  float*  o    = (float*)w;  w += NTOK * 4;
  ushort* t0b  = (ushort*)w; w += NTOK * 2;
  ushort* qkv  = (ushort*)w; w += (size_t)BB * SQl * 3 * DD * 2;
  ushort* kc   = (ushort*)w; w += (size_t)BB * SQl * 6 * DD * 2;
  ushort* vc   = (ushort*)w; w += (size_t)BB * SQl * 6 * DD * 2;
  ushort* kb   = (ushort*)w; w += NTOK * 2;
  ushort* vb   = (ushort*)w; w += NTOK * 2;
  ushort* fbb  = (ushort*)w; w += (size_t)BB * SQl * FFD * 2;
  ushort* wt   = (ushort*)w; w += 48 * MEL * 2;
  ushort* wt1  = (ushort*)w; w += (size_t)NL * DD * FFD * 2;
  ushort* wt2  = (ushort*)w; w += (size_t)NL * FFD * DD * 2;

  const int M = BB * SQl;                        // 6400
  const BiasP nob = {{nullptr, nullptr, nullptr, nullptr, nullptr, nullptr}};

  embed_pe_kernel<<<(int)(NTOK / 256), 256, 0, stream>>>(qids, emb, o);
  cvt_bf16_kernel<<<(int)(NTOK / 8 + 255) / 256, 256, 0, stream>>>(key,   kb, (int)(NTOK / 8));
  cvt_bf16_kernel<<<(int)(NTOK / 8 + 255) / 256, 256, 0, stream>>>(value, vb, (int)(NTOK / 8));

  // all weight transposes up front (3 launches)
  P8 p8 = {{Wq_s, Wk_s, Wv_s, Wo_s, Wq_c, Wk_c, Wv_c, Wo_c}};
  transpose48_kernel<<<dim3(32, 32, 48), 256, 0, stream>>>(p8, wt);
  transposeW_kernel<<<dim3(FFD / 32, DD / 32, NL), 256, 0, stream>>>(W1, wt1, DD, FFD);
  transposeW_kernel<<<dim3(DD / 32, FFD / 32, NL), 256, 0, stream>>>(W2, wt2, FFD, DD);

  ushort* wtQKV = wt;                 // [l][3M]
  ushort* wtOs  = wt + 18 * MEL;      // [l][1M]
  ushort* wtQc  = wt + 24 * MEL;
  ushort* wtKc  = wt + 30 * MEL;
  ushort* wtVc  = wt + 36 * MEL;
  ushort* wtOc  = wt + 42 * MEL;

  // cross-attention K/V for ALL layers (layer-invariant A): two N=6144 GEMMs
  {
    BiasP bk6, bv6;
#pragma unroll
    for (int l = 0; l < NL; ++l) { bk6.p[l] = bk_c + l * DD; bv6.p[l] = bv_c + l * DD; }
    launch_g(kb, wtKc, bk6, nullptr, kc, M, 6 * DD, DD, 6 * DD, 3, stream);
    launch_g(vb, wtVc, bv6, nullptr, vc, M, 6 * DD, DD, 6 * DD, 3, stream);
  }

  for (int l = 0; l < NL; ++l) {
    // ---- self-attention ----
    ln4_kernel<1><<<M / 4, 256, 0, stream>>>(o, ln1_g + l * DD, ln1_b + l * DD, nullptr, t0b);
    BiasP bqkv = {{bq_s + l * DD, bk_s + l * DD, bv_s + l * DD, nullptr, nullptr, nullptr}};
    launch_g(t0b, wtQKV + l * 3 * MEL, bqkv, nullptr, qkv, M, 3 * DD, DD, 3 * DD, 3, stream);
    attn_mfma_kernel<1><<<BB * NH, 256, 0, stream>>>(qkv, 3 * DD, qkv + DD, 3 * DD,
                                                     qkv + 2 * DD, 3 * DD, qids, t0b);
    launch_g(t0b, wtOs + l * MEL, nob, o, nullptr, M, DD, DD, DD, 1, stream);

    // ---- cross-attention ----
    ln4_kernel<1><<<M / 4, 256, 0, stream>>>(o, ln2_g + l * DD, ln2_b + l * DD, nullptr, t0b);
    BiasP bqc = {{bq_c + l * DD, nullptr, nullptr, nullptr, nullptr, nullptr}};
    launch_g(t0b, wtQc + l * MEL, bqc, nullptr, qkv, M, DD, DD, 3 * DD, 3, stream);
    attn_mfma_kernel<0><<<BB * NH, 256, 0, stream>>>(qkv, 3 * DD, kc + l * DD, 6 * DD,
                                                     vc + l * DD, 6 * DD, nullptr, t0b);
    launch_g(t0b, wtOc + l * MEL, nob, o, nullptr, M, DD, DD, DD, 1, stream);

    // ---- feed-forward ----
    ln4_kernel<1><<<M / 4, 256, 0, stream>>>(o, ln3_g + l * DD, ln3_b + l * DD, nullptr, t0b);
    BiasP bf1p = {{bf1 + l * FFD, bf1 + l * FFD + DD, nullptr, nullptr, nullptr, nullptr}};
    launch_g(t0b, wt1 + (size_t)l * DD * FFD, bf1p, nullptr, fbb, M, FFD, DD, FFD, 2, stream);
    BiasP bf2p = {{bf2 + l * DD, nullptr, nullptr, nullptr, nullptr, nullptr}};
    launch_g(fbb, wt2 + (size_t)l * FFD * DD, bf2p, o, nullptr, M, DD, FFD, DD, 1, stream);
  }

  ln4_kernel<0><<<M / 4, 256, 0, stream>>>(o, lnf_g, lnf_b, (float*)d_out, nullptr);
}